// Round 6
// baseline (760.637 us; speedup 1.0000x reference)
//
#include <hip/hip_runtime.h>

// GCN decoder. CSR build is ATOMIC-FREE (gfx950 global atomics write through to
// memory-side at ~32B/op — measured 106MB WRITE_SIZE for 3.2M atomics).
// Two-level counting sort: coarse bins (dst>>7) via LDS histograms, then per-bin
// fine CSR with LDS scan/cursors. Same machinery (keys only) gives the src
// out-degree histogram for norm_src. Then [GEMM(MFMA bf16-split) -> aggregate]x3.

constexpr int D0 = 256, D1 = 128, D2 = 64;
constexpr int NB = 1024;   // coarse bins
constexpr int BSH = 7;     // bin = key >> 7 (128 nodes per bin)
constexpr int EBLK = 2048; // edges per block in hist/partition kernels

typedef __attribute__((ext_vector_type(2))) float f32x2;
typedef __attribute__((ext_vector_type(4))) float f32x4;
typedef __attribute__((ext_vector_type(8))) short short8;

__device__ inline unsigned short f2bf(float f) {
  unsigned u = __builtin_bit_cast(unsigned, f);
  u += 0x7fffu + ((u >> 16) & 1u);
  return (unsigned short)(u >> 16);
}
__device__ inline float bf2f(unsigned short h) {
  unsigned u = ((unsigned)h) << 16;
  return __builtin_bit_cast(float, u);
}
__device__ inline int rdlane_i(int v, int l) { return __builtin_amdgcn_readlane(v, l); }
__device__ inline float rdlane_f(float v, int l) {
  return __builtin_bit_cast(float, __builtin_amdgcn_readlane(__builtin_bit_cast(int, v), l));
}

// ---------------- coarse histogram: per-block LDS hist of key>>BSH ----------------
__global__ void k_chist(const int* __restrict__ key, int* __restrict__ bc, int E) {
  __shared__ int h[NB];
  for (int i = threadIdx.x; i < NB; i += 256) h[i] = 0;
  __syncthreads();
  int e0 = blockIdx.x * EBLK, e1 = min(e0 + EBLK, E);
  for (int i = e0 + threadIdx.x; i < e1; i += 256) atomicAdd(&h[key[i] >> BSH], 1);
  __syncthreads();
  for (int i = threadIdx.x; i < NB; i += 256) bc[blockIdx.x * NB + i] = h[i];
}

// ---------------- scan: per-(block,bin) bases (in-place) + coarse bin offsets ----------------
__global__ void k_cscan(int* __restrict__ bc, int nbk, int* __restrict__ cbase,
                        int* __restrict__ offs_end, int E) {
  __shared__ int wsum[16];
  int bin = threadIdx.x;  // 1024 threads
  int sum = 0;
  for (int b = 0; b < nbk; ++b) {
    int idx = b * NB + bin;
    int v = bc[idx];
    bc[idx] = sum;
    sum += v;
  }
  int lane = bin & 63, wid = bin >> 6;
  int x = sum;
#pragma unroll
  for (int d = 1; d < 64; d <<= 1) { int t = __shfl_up(x, d); if (lane >= d) x += t; }
  if (lane == 63) wsum[wid] = x;
  __syncthreads();
  if (wid == 0 && lane < 16) {
    int s = wsum[lane];
#pragma unroll
    for (int d = 1; d < 16; d <<= 1) { int t = __shfl_up(s, d, 16); if (lane >= d) s += t; }
    wsum[lane] = s;
  }
  __syncthreads();
  int excl = x - sum + (wid ? wsum[wid - 1] : 0);
  cbase[bin] = excl;
  if (bin == NB - 1) cbase[NB] = excl + sum;
  if (bin == 0 && offs_end) *offs_end = E;
}

// ---------------- coarse partition, payload records (dst side) ----------------
// rec.x = src | (dst&127)<<17   (src < 2^17), rec.y = bits(ew)
__global__ void k_cpart(const int* __restrict__ dst, const int* __restrict__ srcv,
                        const float* __restrict__ ew, const int* __restrict__ bc,
                        const int* __restrict__ cbase, int2* __restrict__ recs, int E) {
  __shared__ int cur[NB];
  for (int i = threadIdx.x; i < NB; i += 256) cur[i] = cbase[i] + bc[blockIdx.x * NB + i];
  __syncthreads();
  int e0 = blockIdx.x * EBLK, e1 = min(e0 + EBLK, E);
  for (int i = e0 + threadIdx.x; i < e1; i += 256) {
    int d = dst[i];
    int p = atomicAdd(&cur[d >> BSH], 1);
    recs[p] = int2{srcv[i] | ((d & 127) << 17), __builtin_bit_cast(int, ew[i])};
  }
}

// ---------------- coarse partition, key-only records (src side) ----------------
__global__ void k_cpart1(const int* __restrict__ key, const int* __restrict__ bc,
                         const int* __restrict__ cbase, int* __restrict__ recs, int E) {
  __shared__ int cur[NB];
  for (int i = threadIdx.x; i < NB; i += 256) cur[i] = cbase[i] + bc[blockIdx.x * NB + i];
  __syncthreads();
  int e0 = blockIdx.x * EBLK, e1 = min(e0 + EBLK, E);
  for (int i = e0 + threadIdx.x; i < e1; i += 256) {
    int k = key[i];
    int p = atomicAdd(&cur[k >> BSH], 1);
    recs[p] = k;
  }
}

// ---------------- fine CSR per coarse bin: offs, nd, ordered esw ----------------
__global__ void k_fine(const int2* __restrict__ recs, const int* __restrict__ cbase,
                       int2* __restrict__ esw, int* __restrict__ offs,
                       float* __restrict__ nd, int N) {
  __shared__ int h[128], cur[128];
  __shared__ int w0tot;
  int bin = blockIdx.x;
  int r0 = cbase[bin], r1 = cbase[bin + 1];
  int t = threadIdx.x;
  if (t < 128) h[t] = 0;
  __syncthreads();
  for (int i = r0 + t; i < r1; i += 256) atomicAdd(&h[recs[i].x >> 17], 1);
  __syncthreads();
  int v = 0, x = 0;
  if (t < 128) {
    v = h[t];
    x = v;
#pragma unroll
    for (int d = 1; d < 64; d <<= 1) { int tt = __shfl_up(x, d); if ((t & 63) >= d) x += tt; }
    if (t == 63) w0tot = x;
  }
  __syncthreads();
  if (t < 128) {
    int excl = x - v + (t >= 64 ? w0tot : 0);
    int node = bin * 128 + t;
    if (node < N) {
      offs[node] = r0 + excl;
      int d = v < 1 ? 1 : v;
      nd[node] = (float)(1.0 / sqrt((double)d));
    }
    cur[t] = r0 + excl;
  }
  __syncthreads();
  for (int i = r0 + t; i < r1; i += 256) {
    int2 rc = recs[i];
    int p = atomicAdd(&cur[rc.x >> 17], 1);
    esw[p] = int2{rc.x & 0x1ffff, rc.y};
  }
}

// ---------------- fine histogram per coarse bin (src side): ns only ----------------
__global__ void k_fineh(const int* __restrict__ recs, const int* __restrict__ cbase,
                        float* __restrict__ ns, int N) {
  __shared__ int h[128];
  int bin = blockIdx.x;
  int r0 = cbase[bin], r1 = cbase[bin + 1];
  int t = threadIdx.x;
  if (t < 128) h[t] = 0;
  __syncthreads();
  for (int i = r0 + t; i < r1; i += 256) atomicAdd(&h[recs[i] & 127], 1);
  __syncthreads();
  if (t < 128) {
    int node = bin * 128 + t;
    if (node < N) {
      int d = h[t] < 1 ? 1 : h[t];
      ns[node] = (float)(1.0 / sqrt((double)d));
    }
  }
}

// ---------------- W split: W[K][N] fp32 -> Wt_hi/Wt_lo [N][K] bf16 ----------------
__global__ void k_wsplit(const float* __restrict__ W, short* __restrict__ hi,
                         short* __restrict__ lo, int K, int N) {
  int t = blockIdx.x * blockDim.x + threadIdx.x;
  if (t < K * N) {
    int k = t / N, n = t % N;
    float f = W[t];
    unsigned short h = f2bf(f);
    hi[(size_t)n * K + k] = (short)h;
    lo[(size_t)n * K + k] = (short)f2bf(f - bf2f(h));
  }
}

// ---------------- MFMA GEMM: C[M,N] = (A * ns[:,None]) @ W ----------------
template <int K, int N, int WR, int WC>
__launch_bounds__(256, 2)
__global__ void k_gemm_mfma(const float* __restrict__ A, const float* __restrict__ ns,
                            const short* __restrict__ Wth, const short* __restrict__ Wtl,
                            float* __restrict__ C, int M) {
  constexpr int MR = 128 / WR / 16;
  constexpr int NC = N / WC / 16;
  __shared__ short8 Ah[4 * 128], Al[4 * 128];
  __shared__ short8 Bh[4 * N], Bl[4 * N];
  const int t = threadIdx.x;
  const int block_row = blockIdx.x * 128;
  const int lane = t & 63, wid = t >> 6;
  const int wr = wid / WC, wc = wid % WC;
  const int rowbase = wr * (128 / WR), colbase = wc * (N / WC);
  const int c = lane >> 4, lr = lane & 15;
  f32x4 acc[MR][NC] = {};
  const int r = t & 127;
  const int grow = block_row + r;
  float nsv = 0.f;
  if (t < 128 && grow < M) nsv = ns[grow];

  for (int k0 = 0; k0 < K; k0 += 32) {
    if (t < 128) {
      f32x4 v[8];
      if (grow < M) {
        const f32x4* ap = (const f32x4*)(A + (size_t)grow * K + k0);
#pragma unroll
        for (int i = 0; i < 8; ++i) v[i] = ap[i] * nsv;
      } else {
#pragma unroll
        for (int i = 0; i < 8; ++i) v[i] = f32x4{0.f, 0.f, 0.f, 0.f};
      }
#pragma unroll
      for (int cc = 0; cc < 4; ++cc) {
        short8 hi, lo;
#pragma unroll
        for (int i = 0; i < 8; ++i) {
          float f = v[cc * 2 + (i >> 2)][i & 3];
          unsigned short h = f2bf(f);
          hi[i] = (short)h;
          lo[i] = (short)f2bf(f - bf2f(h));
        }
        Ah[cc * 128 + r] = hi;
        Al[cc * 128 + r] = lo;
      }
    } else {
      const int tt = t - 128;
#pragma unroll
      for (int id = tt; id < N * 4; id += 128) {
        int col = id & (N - 1);
        int cb = id / N;
        Bh[cb * N + col] = *(const short8*)(Wth + (size_t)col * K + k0 + cb * 8);
        Bl[cb * N + col] = *(const short8*)(Wtl + (size_t)col * K + k0 + cb * 8);
      }
    }
    __syncthreads();
    short8 ah[MR], al[MR], bh[NC], bl[NC];
#pragma unroll
    for (int m = 0; m < MR; ++m) {
      int row = rowbase + m * 16 + lr;
      ah[m] = Ah[c * 128 + row];
      al[m] = Al[c * 128 + row];
    }
#pragma unroll
    for (int n = 0; n < NC; ++n) {
      int col = colbase + n * 16 + lr;
      bh[n] = Bh[c * N + col];
      bl[n] = Bl[c * N + col];
    }
#pragma unroll
    for (int m = 0; m < MR; ++m)
#pragma unroll
      for (int n = 0; n < NC; ++n) {
        acc[m][n] = __builtin_amdgcn_mfma_f32_16x16x32_bf16(ah[m], bh[n], acc[m][n], 0, 0, 0);
        acc[m][n] = __builtin_amdgcn_mfma_f32_16x16x32_bf16(ah[m], bl[n], acc[m][n], 0, 0, 0);
        acc[m][n] = __builtin_amdgcn_mfma_f32_16x16x32_bf16(al[m], bh[n], acc[m][n], 0, 0, 0);
      }
    __syncthreads();
  }
#pragma unroll
  for (int m = 0; m < MR; ++m) {
#pragma unroll
    for (int j = 0; j < 4; ++j) {
      int row = block_row + rowbase + m * 16 + (lane >> 4) * 4 + j;
      if (row < M) {
#pragma unroll
        for (int n = 0; n < NC; ++n)
          C[(size_t)row * N + colbase + n * 16 + lr] = acc[m][n][j];
      }
    }
  }
}

// ---------------- aggregation D=128: wave/node, packed edges, unroll-16 gathers ----------------
__global__ void k_agg128(const float* __restrict__ h, const int* __restrict__ offs,
                         const int2* __restrict__ esw, const float* __restrict__ nd,
                         const float* __restrict__ bias, float* __restrict__ out, int M) {
  int w = blockIdx.x * (blockDim.x >> 6) + (threadIdx.x >> 6);
  int lane = threadIdx.x & 63;
  if (w >= M) return;
  int s0 = offs[w], s1 = offs[w + 1];
  const f32x2* hp = (const f32x2*)h;
  float a0 = 0.f, a1 = 0.f;
  for (int base = s0; base < s1; base += 64) {
    int kk = base + lane;
    int sidx = 0;
    float wt = 0.f;
    if (kk < s1) {
      int2 e = esw[kk];
      sidx = e.x;
      wt = __builtin_bit_cast(float, e.y);
    }
    int cnt = min(64, s1 - base);
    for (int jj = 0; jj < cnt; jj += 16) {
      f32x2 v[16];
      float wu[16];
#pragma unroll
      for (int u = 0; u < 16; ++u) {
        int s = rdlane_i(sidx, jj + u);
        wu[u] = rdlane_f(wt, jj + u);
        v[u] = hp[(size_t)(unsigned)s * 64 + lane];
      }
#pragma unroll
      for (int u = 0; u < 16; ++u) {
        a0 += v[u][0] * wu[u];
        a1 += v[u][1] * wu[u];
      }
    }
  }
  float ndv = nd[w];
  f32x2 b = ((const f32x2*)bias)[lane];
  f32x2 rr;
  rr[0] = fmaxf(a0 * ndv + b[0], 0.f);
  rr[1] = fmaxf(a1 * ndv + b[1], 0.f);
  ((f32x2*)out)[(size_t)w * 64 + lane] = rr;
}

// ---------------- aggregation D=64 fused with 64->1 matvec ----------------
__global__ void k_agg64mv(const float* __restrict__ h, const int* __restrict__ offs,
                          const int2* __restrict__ esw, const float* __restrict__ nd,
                          const float* __restrict__ b2, const float* __restrict__ W3,
                          const float* __restrict__ ns, float* __restrict__ h3, int M) {
  int w = blockIdx.x * (blockDim.x >> 6) + (threadIdx.x >> 6);
  int lane = threadIdx.x & 63;
  if (w >= M) return;
  int s0 = offs[w], s1 = offs[w + 1];
  float acc = 0.f;
  for (int base = s0; base < s1; base += 64) {
    int kk = base + lane;
    int sidx = 0;
    float wt = 0.f;
    if (kk < s1) {
      int2 e = esw[kk];
      sidx = e.x;
      wt = __builtin_bit_cast(float, e.y);
    }
    int cnt = min(64, s1 - base);
    for (int jj = 0; jj < cnt; jj += 16) {
      float v[16], wu[16];
#pragma unroll
      for (int u = 0; u < 16; ++u) {
        int s = rdlane_i(sidx, jj + u);
        wu[u] = rdlane_f(wt, jj + u);
        v[u] = h[(size_t)(unsigned)s * 64 + lane];
      }
#pragma unroll
      for (int u = 0; u < 16; ++u) acc += v[u] * wu[u];
    }
  }
  float r = fmaxf(acc * nd[w] + b2[lane], 0.f);
  float p = r * W3[lane];
#pragma unroll
  for (int d = 32; d; d >>= 1) p += __shfl_xor(p, d);
  if (lane == 0) h3[w] = p * ns[w];
}

// ---------------- final scalar aggregation ----------------
__global__ void k_aggfin(const float* __restrict__ h3, const int* __restrict__ offs,
                         const int2* __restrict__ esw, const float* __restrict__ nd,
                         const float* __restrict__ b3, float* __restrict__ out, int M) {
  int i = blockIdx.x * blockDim.x + threadIdx.x;
  if (i >= M) return;
  int s0 = offs[i], s1 = offs[i + 1];
  float acc = 0.f;
  int k = s0;
  for (; k + 4 <= s1; k += 4) {
    int2 e0 = esw[k], e1 = esw[k + 1], e2 = esw[k + 2], e3 = esw[k + 3];
    acc += h3[e0.x] * __builtin_bit_cast(float, e0.y)
         + h3[e1.x] * __builtin_bit_cast(float, e1.y)
         + h3[e2.x] * __builtin_bit_cast(float, e2.y)
         + h3[e3.x] * __builtin_bit_cast(float, e3.y);
  }
  for (; k < s1; ++k) {
    int2 e = esw[k];
    acc += h3[e.x] * __builtin_bit_cast(float, e.y);
  }
  out[i] = acc * nd[i] + b3[0];
}

extern "C" void kernel_launch(void* const* d_in, const int* in_sizes, int n_in,
                              void* d_out, int out_size, void* d_ws, size_t ws_size,
                              hipStream_t stream) {
  const float* b_z = (const float*)d_in[0];
  const int*   src = (const int*)d_in[1];
  const int*   dst = (const int*)d_in[2];
  const float* ew  = (const float*)d_in[3];
  const float* W1  = (const float*)d_in[5];
  const float* b1  = (const float*)d_in[6];
  const float* W2  = (const float*)d_in[7];
  const float* b2  = (const float*)d_in[8];
  const float* W3  = (const float*)d_in[9];
  const float* b3  = (const float*)d_in[10];
  const int N = in_sizes[0] / D0;
  const int E = in_sizes[1];
  float* out = (float*)d_out;

  char* ws = (char*)d_ws;
  size_t off_b = 0;
  auto alloc = [&](size_t bytes) -> void* {
    void* p = ws + off_b;
    off_b += (bytes + 255) & ~(size_t)255;
    return p;
  };
  const int nbk = (E + EBLK - 1) / EBLK;  // coarse-pass blocks
  int*   bc      = (int*)alloc((size_t)nbk * NB * 4);
  int*   cbase_s = (int*)alloc((size_t)(NB + 1) * 4);
  int*   cbase_d = (int*)alloc((size_t)(NB + 1) * 4);
  int*   offs    = (int*)alloc((size_t)(N + 1) * 4);
  int2*  esw     = (int2*)alloc((size_t)E * 8);
  float* nsrc    = (float*)alloc((size_t)N * 4);
  float* ndst    = (float*)alloc((size_t)N * 4);
  float* h1      = (float*)alloc((size_t)N * D1 * 4);
  float* z1      = (float*)alloc((size_t)N * D1 * 4);
  float* h3      = (float*)alloc((size_t)N * 4);
  short* wt1h    = (short*)alloc((size_t)D0 * D1 * 2);
  short* wt1l    = (short*)alloc((size_t)D0 * D1 * 2);
  short* wt2h    = (short*)alloc((size_t)D1 * D2 * 2);
  short* wt2l    = (short*)alloc((size_t)D1 * D2 * 2);
  float* h2     = h1;          // layer-2 GEMM output reuses h1 (dead after agg128)
  int2*  recs_d = (int2*)h1;   // dst-partition records: dead before GEMM1 writes h1
  int*   recs_s = (int*)z1;    // src-partition records: dead before agg128 writes z1

  // --- src side: out-degree histogram -> ns (needed by GEMMs) ---
  k_chist<<<nbk, 256, 0, stream>>>(src, bc, E);
  k_cscan<<<1, 1024, 0, stream>>>(bc, nbk, cbase_s, nullptr, E);
  k_cpart1<<<nbk, 256, 0, stream>>>(src, bc, cbase_s, recs_s, E);
  k_fineh<<<NB, 256, 0, stream>>>(recs_s, cbase_s, nsrc, N);
  // --- dst side: full CSR (offs, esw) + nd ---
  k_chist<<<nbk, 256, 0, stream>>>(dst, bc, E);
  k_cscan<<<1, 1024, 0, stream>>>(bc, nbk, cbase_d, &offs[N], E);
  k_cpart<<<nbk, 256, 0, stream>>>(dst, src, ew, bc, cbase_d, recs_d, E);
  k_fine<<<NB, 256, 0, stream>>>(recs_d, cbase_d, esw, offs, ndst, N);

  k_wsplit<<<(D0 * D1 + 255) / 256, 256, 0, stream>>>(W1, wt1h, wt1l, D0, D1);
  k_wsplit<<<(D1 * D2 + 255) / 256, 256, 0, stream>>>(W2, wt2h, wt2l, D1, D2);

  const int gemm_grid = (N + 127) / 128;
  // layer 1: 256 -> 128
  k_gemm_mfma<D0, D1, 2, 2><<<gemm_grid, 256, 0, stream>>>(b_z, nsrc, wt1h, wt1l, h1, N);
  k_agg128<<<(N + 3) / 4, 256, 0, stream>>>(h1, offs, esw, ndst, b1, z1, N);
  // layer 2: 128 -> 64
  k_gemm_mfma<D1, D2, 4, 1><<<gemm_grid, 256, 0, stream>>>(z1, nsrc, wt2h, wt2l, h2, N);
  // layer-2 agg fused with layer-3 projection (64->1 matvec)
  k_agg64mv<<<(N + 3) / 4, 256, 0, stream>>>(h2, offs, esw, ndst, b2, W3, nsrc, h3, N);
  // final scalar aggregation
  k_aggfin<<<(N + 255) / 256, 256, 0, stream>>>(h3, offs, esw, ndst, b3, out, N);
}

// Round 7
// 361.697 us; speedup vs baseline: 2.1030x; 2.1030x over previous
//
#include <hip/hip_runtime.h>

// GCN decoder. Atomic-free CSR build via two-level counting sort:
//   chist2 (merged src+dst LDS histograms) -> binscan (parallel column scan,
//   1 block/bin) -> btscan (1024-bin scan) -> cpart (LDS-cursor partition) ->
//   fine (per-bin CSR + norms). Then [GEMM(MFMA bf16-split) -> aggregate]x3.

constexpr int D0 = 256, D1 = 128, D2 = 64;
constexpr int NB = 1024;   // coarse bins
constexpr int BSH = 7;     // bin = key >> 7 (128 nodes per bin)
constexpr int EBLK = 4096; // edges per block in hist/partition kernels

typedef __attribute__((ext_vector_type(2))) float f32x2;
typedef __attribute__((ext_vector_type(4))) float f32x4;
typedef __attribute__((ext_vector_type(8))) short short8;

__device__ inline unsigned short f2bf(float f) {
  unsigned u = __builtin_bit_cast(unsigned, f);
  u += 0x7fffu + ((u >> 16) & 1u);
  return (unsigned short)(u >> 16);
}
__device__ inline float bf2f(unsigned short h) {
  unsigned u = ((unsigned)h) << 16;
  return __builtin_bit_cast(float, u);
}
__device__ inline int rdlane_i(int v, int l) { return __builtin_amdgcn_readlane(v, l); }
__device__ inline float rdlane_f(float v, int l) {
  return __builtin_bit_cast(float, __builtin_amdgcn_readlane(__builtin_bit_cast(int, v), l));
}

// ---------------- merged coarse histograms: src and dst in one edge pass ----------------
__global__ void k_chist2(const int* __restrict__ src, const int* __restrict__ dst,
                         int* __restrict__ bc_s, int* __restrict__ bc_d, int E) {
  __shared__ int hs[NB], hd[NB];
  for (int i = threadIdx.x; i < NB; i += 256) { hs[i] = 0; hd[i] = 0; }
  __syncthreads();
  int e0 = blockIdx.x * EBLK, e1 = min(e0 + EBLK, E);
  for (int i = e0 + threadIdx.x; i < e1; i += 256) {
    atomicAdd(&hs[src[i] >> BSH], 1);
    atomicAdd(&hd[dst[i] >> BSH], 1);
  }
  __syncthreads();
  for (int i = threadIdx.x; i < NB; i += 256) {
    bc_s[blockIdx.x * NB + i] = hs[i];
    bc_d[blockIdx.x * NB + i] = hd[i];
  }
}

// ---------------- parallel column scan: one block per bin ----------------
// bc[b][bin] <- exclusive prefix over b; bintot[bin] = column total.
__global__ void k_binscan(int* __restrict__ bc_s, int* __restrict__ bt_s,
                          int* __restrict__ bc_d, int* __restrict__ bt_d, int nbk) {
  __shared__ int ws[4];
  int* bc = blockIdx.y ? bc_d : bc_s;
  int* bt = blockIdx.y ? bt_d : bt_s;
  const int bin = blockIdx.x;
  const int t = threadIdx.x;
  const int chunk = (nbk + 255) / 256;
  const int b0 = t * chunk, b1 = min(b0 + chunk, nbk);
  int s = 0;
  for (int b = b0; b < b1; ++b) s += bc[b * NB + bin];
  int lane = t & 63, wid = t >> 6;
  int x = s;
#pragma unroll
  for (int d = 1; d < 64; d <<= 1) { int tt = __shfl_up(x, d); if (lane >= d) x += tt; }
  if (lane == 63) ws[wid] = x;
  __syncthreads();
  int wexcl = 0;
  for (int q = 0; q < wid; ++q) wexcl += ws[q];
  int run = wexcl + x - s;  // exclusive prefix for this thread's chunk
  for (int b = b0; b < b1; ++b) {
    int v = bc[b * NB + bin];
    bc[b * NB + bin] = run;
    run += v;
  }
  if (t == 255) bt[bin] = run;  // grand total of this bin
}

// ---------------- scan of 1024 bin totals (block 0: src, block 1: dst) ----------------
__global__ void k_btscan(const int* __restrict__ bt_s, int* __restrict__ cbase_s,
                         const int* __restrict__ bt_d, int* __restrict__ cbase_d,
                         int* __restrict__ offs_end, int E) {
  __shared__ int wsum[16];
  const int* bt = blockIdx.x ? bt_d : bt_s;
  int* cbase = blockIdx.x ? cbase_d : cbase_s;
  int tid = threadIdx.x, lane = tid & 63, wid = tid >> 6;
  int v = bt[tid];
  int x = v;
#pragma unroll
  for (int d = 1; d < 64; d <<= 1) { int t = __shfl_up(x, d); if (lane >= d) x += t; }
  if (lane == 63) wsum[wid] = x;
  __syncthreads();
  if (wid == 0 && lane < 16) {
    int s = wsum[lane];
#pragma unroll
    for (int d = 1; d < 16; d <<= 1) { int t = __shfl_up(s, d, 16); if (lane >= d) s += t; }
    wsum[lane] = s;
  }
  __syncthreads();
  int excl = x - v + (wid ? wsum[wid - 1] : 0);
  cbase[tid] = excl;
  if (tid == NB - 1) cbase[NB] = E;
  if (blockIdx.x == 1 && tid == 0) *offs_end = E;
}

// ---------------- coarse partition, payload records (dst side) ----------------
// rec.x = src | (dst&127)<<17   (src < 2^17), rec.y = bits(ew)
__global__ void k_cpart(const int* __restrict__ dst, const int* __restrict__ srcv,
                        const float* __restrict__ ew, const int* __restrict__ bc,
                        const int* __restrict__ cbase, int2* __restrict__ recs, int E) {
  __shared__ int cur[NB];
  for (int i = threadIdx.x; i < NB; i += 256) cur[i] = cbase[i] + bc[blockIdx.x * NB + i];
  __syncthreads();
  int e0 = blockIdx.x * EBLK, e1 = min(e0 + EBLK, E);
  for (int i = e0 + threadIdx.x; i < e1; i += 256) {
    int d = dst[i];
    int p = atomicAdd(&cur[d >> BSH], 1);
    recs[p] = int2{srcv[i] | ((d & 127) << 17), __builtin_bit_cast(int, ew[i])};
  }
}

// ---------------- coarse partition, key-only records (src side) ----------------
__global__ void k_cpart1(const int* __restrict__ key, const int* __restrict__ bc,
                         const int* __restrict__ cbase, int* __restrict__ recs, int E) {
  __shared__ int cur[NB];
  for (int i = threadIdx.x; i < NB; i += 256) cur[i] = cbase[i] + bc[blockIdx.x * NB + i];
  __syncthreads();
  int e0 = blockIdx.x * EBLK, e1 = min(e0 + EBLK, E);
  for (int i = e0 + threadIdx.x; i < e1; i += 256) {
    int k = key[i];
    int p = atomicAdd(&cur[k >> BSH], 1);
    recs[p] = k;
  }
}

// ---------------- fine CSR per coarse bin: offs, nd, ordered esw ----------------
__global__ void k_fine(const int2* __restrict__ recs, const int* __restrict__ cbase,
                       int2* __restrict__ esw, int* __restrict__ offs,
                       float* __restrict__ nd, int N) {
  __shared__ int h[128], cur[128];
  __shared__ int w0tot;
  int bin = blockIdx.x;
  int r0 = cbase[bin], r1 = cbase[bin + 1];
  int t = threadIdx.x;
  if (t < 128) h[t] = 0;
  __syncthreads();
  for (int i = r0 + t; i < r1; i += 256) atomicAdd(&h[recs[i].x >> 17], 1);
  __syncthreads();
  int v = 0, x = 0;
  if (t < 128) {
    v = h[t];
    x = v;
#pragma unroll
    for (int d = 1; d < 64; d <<= 1) { int tt = __shfl_up(x, d); if ((t & 63) >= d) x += tt; }
    if (t == 63) w0tot = x;
  }
  __syncthreads();
  if (t < 128) {
    int excl = x - v + (t >= 64 ? w0tot : 0);
    int node = bin * 128 + t;
    if (node < N) {
      offs[node] = r0 + excl;
      int d = v < 1 ? 1 : v;
      nd[node] = (float)(1.0 / sqrt((double)d));
    }
    cur[t] = r0 + excl;
  }
  __syncthreads();
  for (int i = r0 + t; i < r1; i += 256) {
    int2 rc = recs[i];
    int p = atomicAdd(&cur[rc.x >> 17], 1);
    esw[p] = int2{rc.x & 0x1ffff, rc.y};
  }
}

// ---------------- fine histogram per coarse bin (src side): ns only ----------------
__global__ void k_fineh(const int* __restrict__ recs, const int* __restrict__ cbase,
                        float* __restrict__ ns, int N) {
  __shared__ int h[128];
  int bin = blockIdx.x;
  int r0 = cbase[bin], r1 = cbase[bin + 1];
  int t = threadIdx.x;
  if (t < 128) h[t] = 0;
  __syncthreads();
  for (int i = r0 + t; i < r1; i += 256) atomicAdd(&h[recs[i] & 127], 1);
  __syncthreads();
  if (t < 128) {
    int node = bin * 128 + t;
    if (node < N) {
      int d = h[t] < 1 ? 1 : h[t];
      ns[node] = (float)(1.0 / sqrt((double)d));
    }
  }
}

// ---------------- W split: W[K][N] fp32 -> Wt_hi/Wt_lo [N][K] bf16 ----------------
__global__ void k_wsplit(const float* __restrict__ W, short* __restrict__ hi,
                         short* __restrict__ lo, int K, int N) {
  int t = blockIdx.x * blockDim.x + threadIdx.x;
  if (t < K * N) {
    int k = t / N, n = t % N;
    float f = W[t];
    unsigned short h = f2bf(f);
    hi[(size_t)n * K + k] = (short)h;
    lo[(size_t)n * K + k] = (short)f2bf(f - bf2f(h));
  }
}

// ---------------- MFMA GEMM: C[M,N] = (A * ns[:,None]) @ W ----------------
template <int K, int N, int WR, int WC>
__launch_bounds__(256, 2)
__global__ void k_gemm_mfma(const float* __restrict__ A, const float* __restrict__ ns,
                            const short* __restrict__ Wth, const short* __restrict__ Wtl,
                            float* __restrict__ C, int M) {
  constexpr int MR = 128 / WR / 16;
  constexpr int NC = N / WC / 16;
  __shared__ short8 Ah[4 * 128], Al[4 * 128];
  __shared__ short8 Bh[4 * N], Bl[4 * N];
  const int t = threadIdx.x;
  const int block_row = blockIdx.x * 128;
  const int lane = t & 63, wid = t >> 6;
  const int wr = wid / WC, wc = wid % WC;
  const int rowbase = wr * (128 / WR), colbase = wc * (N / WC);
  const int c = lane >> 4, lr = lane & 15;
  f32x4 acc[MR][NC] = {};
  const int r = t & 127;
  const int grow = block_row + r;
  float nsv = 0.f;
  if (t < 128 && grow < M) nsv = ns[grow];

  for (int k0 = 0; k0 < K; k0 += 32) {
    if (t < 128) {
      f32x4 v[8];
      if (grow < M) {
        const f32x4* ap = (const f32x4*)(A + (size_t)grow * K + k0);
#pragma unroll
        for (int i = 0; i < 8; ++i) v[i] = ap[i] * nsv;
      } else {
#pragma unroll
        for (int i = 0; i < 8; ++i) v[i] = f32x4{0.f, 0.f, 0.f, 0.f};
      }
#pragma unroll
      for (int cc = 0; cc < 4; ++cc) {
        short8 hi, lo;
#pragma unroll
        for (int i = 0; i < 8; ++i) {
          float f = v[cc * 2 + (i >> 2)][i & 3];
          unsigned short h = f2bf(f);
          hi[i] = (short)h;
          lo[i] = (short)f2bf(f - bf2f(h));
        }
        Ah[cc * 128 + r] = hi;
        Al[cc * 128 + r] = lo;
      }
    } else {
      const int tt = t - 128;
#pragma unroll
      for (int id = tt; id < N * 4; id += 128) {
        int col = id & (N - 1);
        int cb = id / N;
        Bh[cb * N + col] = *(const short8*)(Wth + (size_t)col * K + k0 + cb * 8);
        Bl[cb * N + col] = *(const short8*)(Wtl + (size_t)col * K + k0 + cb * 8);
      }
    }
    __syncthreads();
    short8 ah[MR], al[MR], bh[NC], bl[NC];
#pragma unroll
    for (int m = 0; m < MR; ++m) {
      int row = rowbase + m * 16 + lr;
      ah[m] = Ah[c * 128 + row];
      al[m] = Al[c * 128 + row];
    }
#pragma unroll
    for (int n = 0; n < NC; ++n) {
      int col = colbase + n * 16 + lr;
      bh[n] = Bh[c * N + col];
      bl[n] = Bl[c * N + col];
    }
#pragma unroll
    for (int m = 0; m < MR; ++m)
#pragma unroll
      for (int n = 0; n < NC; ++n) {
        acc[m][n] = __builtin_amdgcn_mfma_f32_16x16x32_bf16(ah[m], bh[n], acc[m][n], 0, 0, 0);
        acc[m][n] = __builtin_amdgcn_mfma_f32_16x16x32_bf16(ah[m], bl[n], acc[m][n], 0, 0, 0);
        acc[m][n] = __builtin_amdgcn_mfma_f32_16x16x32_bf16(al[m], bh[n], acc[m][n], 0, 0, 0);
      }
    __syncthreads();
  }
#pragma unroll
  for (int m = 0; m < MR; ++m) {
#pragma unroll
    for (int j = 0; j < 4; ++j) {
      int row = block_row + rowbase + m * 16 + (lane >> 4) * 4 + j;
      if (row < M) {
#pragma unroll
        for (int n = 0; n < NC; ++n)
          C[(size_t)row * N + colbase + n * 16 + lr] = acc[m][n][j];
      }
    }
  }
}

// ---------------- aggregation D=128: wave/node, packed edges, unroll-16 gathers ----------------
__global__ void k_agg128(const float* __restrict__ h, const int* __restrict__ offs,
                         const int2* __restrict__ esw, const float* __restrict__ nd,
                         const float* __restrict__ bias, float* __restrict__ out, int M) {
  int w = blockIdx.x * (blockDim.x >> 6) + (threadIdx.x >> 6);
  int lane = threadIdx.x & 63;
  if (w >= M) return;
  int s0 = offs[w], s1 = offs[w + 1];
  const f32x2* hp = (const f32x2*)h;
  float a0 = 0.f, a1 = 0.f;
  for (int base = s0; base < s1; base += 64) {
    int kk = base + lane;
    int sidx = 0;
    float wt = 0.f;
    if (kk < s1) {
      int2 e = esw[kk];
      sidx = e.x;
      wt = __builtin_bit_cast(float, e.y);
    }
    int cnt = min(64, s1 - base);
    for (int jj = 0; jj < cnt; jj += 16) {
      f32x2 v[16];
      float wu[16];
#pragma unroll
      for (int u = 0; u < 16; ++u) {
        int s = rdlane_i(sidx, jj + u);
        wu[u] = rdlane_f(wt, jj + u);
        v[u] = hp[(size_t)(unsigned)s * 64 + lane];
      }
#pragma unroll
      for (int u = 0; u < 16; ++u) {
        a0 += v[u][0] * wu[u];
        a1 += v[u][1] * wu[u];
      }
    }
  }
  float ndv = nd[w];
  f32x2 b = ((const f32x2*)bias)[lane];
  f32x2 rr;
  rr[0] = fmaxf(a0 * ndv + b[0], 0.f);
  rr[1] = fmaxf(a1 * ndv + b[1], 0.f);
  ((f32x2*)out)[(size_t)w * 64 + lane] = rr;
}

// ---------------- aggregation D=64 fused with 64->1 matvec ----------------
__global__ void k_agg64mv(const float* __restrict__ h, const int* __restrict__ offs,
                          const int2* __restrict__ esw, const float* __restrict__ nd,
                          const float* __restrict__ b2, const float* __restrict__ W3,
                          const float* __restrict__ ns, float* __restrict__ h3, int M) {
  int w = blockIdx.x * (blockDim.x >> 6) + (threadIdx.x >> 6);
  int lane = threadIdx.x & 63;
  if (w >= M) return;
  int s0 = offs[w], s1 = offs[w + 1];
  float acc = 0.f;
  for (int base = s0; base < s1; base += 64) {
    int kk = base + lane;
    int sidx = 0;
    float wt = 0.f;
    if (kk < s1) {
      int2 e = esw[kk];
      sidx = e.x;
      wt = __builtin_bit_cast(float, e.y);
    }
    int cnt = min(64, s1 - base);
    for (int jj = 0; jj < cnt; jj += 16) {
      float v[16], wu[16];
#pragma unroll
      for (int u = 0; u < 16; ++u) {
        int s = rdlane_i(sidx, jj + u);
        wu[u] = rdlane_f(wt, jj + u);
        v[u] = h[(size_t)(unsigned)s * 64 + lane];
      }
#pragma unroll
      for (int u = 0; u < 16; ++u) acc += v[u] * wu[u];
    }
  }
  float r = fmaxf(acc * nd[w] + b2[lane], 0.f);
  float p = r * W3[lane];
#pragma unroll
  for (int d = 32; d; d >>= 1) p += __shfl_xor(p, d);
  if (lane == 0) h3[w] = p * ns[w];
}

// ---------------- final scalar aggregation ----------------
__global__ void k_aggfin(const float* __restrict__ h3, const int* __restrict__ offs,
                         const int2* __restrict__ esw, const float* __restrict__ nd,
                         const float* __restrict__ b3, float* __restrict__ out, int M) {
  int i = blockIdx.x * blockDim.x + threadIdx.x;
  if (i >= M) return;
  int s0 = offs[i], s1 = offs[i + 1];
  float acc = 0.f;
  int k = s0;
  for (; k + 4 <= s1; k += 4) {
    int2 e0 = esw[k], e1 = esw[k + 1], e2 = esw[k + 2], e3 = esw[k + 3];
    acc += h3[e0.x] * __builtin_bit_cast(float, e0.y)
         + h3[e1.x] * __builtin_bit_cast(float, e1.y)
         + h3[e2.x] * __builtin_bit_cast(float, e2.y)
         + h3[e3.x] * __builtin_bit_cast(float, e3.y);
  }
  for (; k < s1; ++k) {
    int2 e = esw[k];
    acc += h3[e.x] * __builtin_bit_cast(float, e.y);
  }
  out[i] = acc * nd[i] + b3[0];
}

extern "C" void kernel_launch(void* const* d_in, const int* in_sizes, int n_in,
                              void* d_out, int out_size, void* d_ws, size_t ws_size,
                              hipStream_t stream) {
  const float* b_z = (const float*)d_in[0];
  const int*   src = (const int*)d_in[1];
  const int*   dst = (const int*)d_in[2];
  const float* ew  = (const float*)d_in[3];
  const float* W1  = (const float*)d_in[5];
  const float* b1  = (const float*)d_in[6];
  const float* W2  = (const float*)d_in[7];
  const float* b2  = (const float*)d_in[8];
  const float* W3  = (const float*)d_in[9];
  const float* b3  = (const float*)d_in[10];
  const int N = in_sizes[0] / D0;
  const int E = in_sizes[1];
  float* out = (float*)d_out;

  char* ws = (char*)d_ws;
  size_t off_b = 0;
  auto alloc = [&](size_t bytes) -> void* {
    void* p = ws + off_b;
    off_b += (bytes + 255) & ~(size_t)255;
    return p;
  };
  const int nbk = (E + EBLK - 1) / EBLK;  // coarse-pass blocks
  int*   bc_s    = (int*)alloc((size_t)nbk * NB * 4);
  int*   bc_d    = (int*)alloc((size_t)nbk * NB * 4);
  int*   bt_s    = (int*)alloc((size_t)NB * 4);
  int*   bt_d    = (int*)alloc((size_t)NB * 4);
  int*   cbase_s = (int*)alloc((size_t)(NB + 1) * 4);
  int*   cbase_d = (int*)alloc((size_t)(NB + 1) * 4);
  int*   offs    = (int*)alloc((size_t)(N + 1) * 4);
  int2*  esw     = (int2*)alloc((size_t)E * 8);
  float* nsrc    = (float*)alloc((size_t)N * 4);
  float* ndst    = (float*)alloc((size_t)N * 4);
  float* h1      = (float*)alloc((size_t)N * D1 * 4);
  float* z1      = (float*)alloc((size_t)N * D1 * 4);
  float* h3      = (float*)alloc((size_t)N * 4);
  short* wt1h    = (short*)alloc((size_t)D0 * D1 * 2);
  short* wt1l    = (short*)alloc((size_t)D0 * D1 * 2);
  short* wt2h    = (short*)alloc((size_t)D1 * D2 * 2);
  short* wt2l    = (short*)alloc((size_t)D1 * D2 * 2);
  float* h2     = h1;          // layer-2 GEMM output reuses h1 (dead after agg128)
  int2*  recs_d = (int2*)h1;   // dst-partition records: dead before GEMM1 writes h1
  int*   recs_s = (int*)z1;    // src-partition records: dead before agg128 writes z1

  // --- CSR build (atomic-free, fully parallel) ---
  k_chist2<<<nbk, 256, 0, stream>>>(src, dst, bc_s, bc_d, E);
  k_binscan<<<dim3(NB, 2), 256, 0, stream>>>(bc_s, bt_s, bc_d, bt_d, nbk);
  k_btscan<<<2, 1024, 0, stream>>>(bt_s, cbase_s, bt_d, cbase_d, &offs[N], E);
  k_cpart1<<<nbk, 256, 0, stream>>>(src, bc_s, cbase_s, recs_s, E);
  k_fineh<<<NB, 256, 0, stream>>>(recs_s, cbase_s, nsrc, N);
  k_cpart<<<nbk, 256, 0, stream>>>(dst, src, ew, bc_d, cbase_d, recs_d, E);
  k_fine<<<NB, 256, 0, stream>>>(recs_d, cbase_d, esw, offs, ndst, N);

  k_wsplit<<<(D0 * D1 + 255) / 256, 256, 0, stream>>>(W1, wt1h, wt1l, D0, D1);
  k_wsplit<<<(D1 * D2 + 255) / 256, 256, 0, stream>>>(W2, wt2h, wt2l, D1, D2);

  const int gemm_grid = (N + 127) / 128;
  // layer 1: 256 -> 128
  k_gemm_mfma<D0, D1, 2, 2><<<gemm_grid, 256, 0, stream>>>(b_z, nsrc, wt1h, wt1l, h1, N);
  k_agg128<<<(N + 3) / 4, 256, 0, stream>>>(h1, offs, esw, ndst, b1, z1, N);
  // layer 2: 128 -> 64
  k_gemm_mfma<D1, D2, 4, 1><<<gemm_grid, 256, 0, stream>>>(z1, nsrc, wt2h, wt2l, h2, N);
  // layer-2 agg fused with layer-3 projection (64->1 matvec)
  k_agg64mv<<<(N + 3) / 4, 256, 0, stream>>>(h2, offs, esw, ndst, b2, W3, nsrc, h3, N);
  // final scalar aggregation
  k_aggfin<<<(N + 255) / 256, 256, 0, stream>>>(h3, offs, esw, ndst, b3, out, N);
}

// Round 8
// 332.885 us; speedup vs baseline: 2.2850x; 1.0866x over previous
//
#include <hip/hip_runtime.h>

// GCN decoder. Atomic-free CSR build (two-level counting sort) ->
// GEMM1(MFMA bf16-split) -> agg128 FUSED with GEMM2 (LDS mini-GEMM epilogue) ->
// agg64+matvec(W3) -> final scalar agg.

constexpr int D0 = 256, D1 = 128, D2 = 64;
constexpr int NB = 1024;   // coarse bins
constexpr int BSH = 7;     // bin = key >> 7 (128 nodes per bin)
constexpr int EBLK = 4096; // edges per block in hist/partition kernels

typedef __attribute__((ext_vector_type(2))) float f32x2;
typedef __attribute__((ext_vector_type(4))) float f32x4;
typedef __attribute__((ext_vector_type(8))) short short8;

__device__ inline unsigned short f2bf(float f) {
  unsigned u = __builtin_bit_cast(unsigned, f);
  u += 0x7fffu + ((u >> 16) & 1u);
  return (unsigned short)(u >> 16);
}
__device__ inline float bf2f(unsigned short h) {
  unsigned u = ((unsigned)h) << 16;
  return __builtin_bit_cast(float, u);
}
__device__ inline int rdlane_i(int v, int l) { return __builtin_amdgcn_readlane(v, l); }
__device__ inline float rdlane_f(float v, int l) {
  return __builtin_bit_cast(float, __builtin_amdgcn_readlane(__builtin_bit_cast(int, v), l));
}

// ---------------- merged coarse histograms: src and dst in one edge pass ----------------
__global__ void k_chist2(const int* __restrict__ src, const int* __restrict__ dst,
                         int* __restrict__ bc_s, int* __restrict__ bc_d, int E) {
  __shared__ int hs[NB], hd[NB];
  for (int i = threadIdx.x; i < NB; i += 256) { hs[i] = 0; hd[i] = 0; }
  __syncthreads();
  int e0 = blockIdx.x * EBLK, e1 = min(e0 + EBLK, E);
  for (int i = e0 + threadIdx.x; i < e1; i += 256) {
    atomicAdd(&hs[src[i] >> BSH], 1);
    atomicAdd(&hd[dst[i] >> BSH], 1);
  }
  __syncthreads();
  for (int i = threadIdx.x; i < NB; i += 256) {
    bc_s[blockIdx.x * NB + i] = hs[i];
    bc_d[blockIdx.x * NB + i] = hd[i];
  }
}

// ---------------- parallel column scan: one block per bin ----------------
__global__ void k_binscan(int* __restrict__ bc_s, int* __restrict__ bt_s,
                          int* __restrict__ bc_d, int* __restrict__ bt_d, int nbk) {
  __shared__ int ws[4];
  int* bc = blockIdx.y ? bc_d : bc_s;
  int* bt = blockIdx.y ? bt_d : bt_s;
  const int bin = blockIdx.x;
  const int t = threadIdx.x;
  const int chunk = (nbk + 255) / 256;
  const int b0 = t * chunk, b1 = min(b0 + chunk, nbk);
  int s = 0;
  for (int b = b0; b < b1; ++b) s += bc[b * NB + bin];
  int lane = t & 63, wid = t >> 6;
  int x = s;
#pragma unroll
  for (int d = 1; d < 64; d <<= 1) { int tt = __shfl_up(x, d); if (lane >= d) x += tt; }
  if (lane == 63) ws[wid] = x;
  __syncthreads();
  int wexcl = 0;
  for (int q = 0; q < wid; ++q) wexcl += ws[q];
  int run = wexcl + x - s;
  for (int b = b0; b < b1; ++b) {
    int v = bc[b * NB + bin];
    bc[b * NB + bin] = run;
    run += v;
  }
  if (t == 255) bt[bin] = run;
}

// ---------------- scan of 1024 bin totals (block 0: src, block 1: dst) ----------------
__global__ void k_btscan(const int* __restrict__ bt_s, int* __restrict__ cbase_s,
                         const int* __restrict__ bt_d, int* __restrict__ cbase_d,
                         int* __restrict__ offs_end, int E) {
  __shared__ int wsum[16];
  const int* bt = blockIdx.x ? bt_d : bt_s;
  int* cbase = blockIdx.x ? cbase_d : cbase_s;
  int tid = threadIdx.x, lane = tid & 63, wid = tid >> 6;
  int v = bt[tid];
  int x = v;
#pragma unroll
  for (int d = 1; d < 64; d <<= 1) { int t = __shfl_up(x, d); if (lane >= d) x += t; }
  if (lane == 63) wsum[wid] = x;
  __syncthreads();
  if (wid == 0 && lane < 16) {
    int s = wsum[lane];
#pragma unroll
    for (int d = 1; d < 16; d <<= 1) { int t = __shfl_up(s, d, 16); if (lane >= d) s += t; }
    wsum[lane] = s;
  }
  __syncthreads();
  int excl = x - v + (wid ? wsum[wid - 1] : 0);
  cbase[tid] = excl;
  if (tid == NB - 1) cbase[NB] = E;
  if (blockIdx.x == 1 && tid == 0) *offs_end = E;
}

// ---------------- merged coarse partition: one edge pass, both sides ----------------
// recs_d.x = src | (dst&127)<<17, recs_d.y = bits(ew); recs_s = src key only.
__global__ void k_cpart2(const int* __restrict__ src, const int* __restrict__ dst,
                         const float* __restrict__ ew,
                         const int* __restrict__ bc_s, const int* __restrict__ cbase_s,
                         const int* __restrict__ bc_d, const int* __restrict__ cbase_d,
                         int* __restrict__ recs_s, int2* __restrict__ recs_d, int E) {
  __shared__ int cs[NB], cd[NB];
  for (int i = threadIdx.x; i < NB; i += 256) {
    cs[i] = cbase_s[i] + bc_s[blockIdx.x * NB + i];
    cd[i] = cbase_d[i] + bc_d[blockIdx.x * NB + i];
  }
  __syncthreads();
  int e0 = blockIdx.x * EBLK, e1 = min(e0 + EBLK, E);
  for (int i = e0 + threadIdx.x; i < e1; i += 256) {
    int s = src[i], d = dst[i];
    int ps = atomicAdd(&cs[s >> BSH], 1);
    recs_s[ps] = s;
    int pd = atomicAdd(&cd[d >> BSH], 1);
    recs_d[pd] = int2{s | ((d & 127) << 17), __builtin_bit_cast(int, ew[i])};
  }
}

// ---------------- fine CSR per coarse bin: offs, nd, ordered esw ----------------
__global__ void k_fine(const int2* __restrict__ recs, const int* __restrict__ cbase,
                       int2* __restrict__ esw, int* __restrict__ offs,
                       float* __restrict__ nd, int N) {
  __shared__ int h[128], cur[128];
  __shared__ int w0tot;
  int bin = blockIdx.x;
  int r0 = cbase[bin], r1 = cbase[bin + 1];
  int t = threadIdx.x;
  if (t < 128) h[t] = 0;
  __syncthreads();
  for (int i = r0 + t; i < r1; i += 256) atomicAdd(&h[recs[i].x >> 17], 1);
  __syncthreads();
  int v = 0, x = 0;
  if (t < 128) {
    v = h[t];
    x = v;
#pragma unroll
    for (int d = 1; d < 64; d <<= 1) { int tt = __shfl_up(x, d); if ((t & 63) >= d) x += tt; }
    if (t == 63) w0tot = x;
  }
  __syncthreads();
  if (t < 128) {
    int excl = x - v + (t >= 64 ? w0tot : 0);
    int node = bin * 128 + t;
    if (node < N) {
      offs[node] = r0 + excl;
      int d = v < 1 ? 1 : v;
      nd[node] = (float)(1.0 / sqrt((double)d));
    }
    cur[t] = r0 + excl;
  }
  __syncthreads();
  for (int i = r0 + t; i < r1; i += 256) {
    int2 rc = recs[i];
    int p = atomicAdd(&cur[rc.x >> 17], 1);
    esw[p] = int2{rc.x & 0x1ffff, rc.y};
  }
}

// ---------------- fine histogram per coarse bin (src side): ns only ----------------
__global__ void k_fineh(const int* __restrict__ recs, const int* __restrict__ cbase,
                        float* __restrict__ ns, int N) {
  __shared__ int h[128];
  int bin = blockIdx.x;
  int r0 = cbase[bin], r1 = cbase[bin + 1];
  int t = threadIdx.x;
  if (t < 128) h[t] = 0;
  __syncthreads();
  for (int i = r0 + t; i < r1; i += 256) atomicAdd(&h[recs[i] & 127], 1);
  __syncthreads();
  if (t < 128) {
    int node = bin * 128 + t;
    if (node < N) {
      int d = h[t] < 1 ? 1 : h[t];
      ns[node] = (float)(1.0 / sqrt((double)d));
    }
  }
}

// ---------------- W split: W[K][N] fp32 -> Wt_hi/Wt_lo [N][K] bf16 ----------------
__global__ void k_wsplit(const float* __restrict__ W, short* __restrict__ hi,
                         short* __restrict__ lo, int K, int N) {
  int t = blockIdx.x * blockDim.x + threadIdx.x;
  if (t < K * N) {
    int k = t / N, n = t % N;
    float f = W[t];
    unsigned short h = f2bf(f);
    hi[(size_t)n * K + k] = (short)h;
    lo[(size_t)n * K + k] = (short)f2bf(f - bf2f(h));
  }
}

// ---------------- MFMA GEMM (layer 1): C[M,N] = (A * ns[:,None]) @ W ----------------
template <int K, int N, int WR, int WC>
__launch_bounds__(256, 2)
__global__ void k_gemm_mfma(const float* __restrict__ A, const float* __restrict__ ns,
                            const short* __restrict__ Wth, const short* __restrict__ Wtl,
                            float* __restrict__ C, int M) {
  constexpr int MR = 128 / WR / 16;
  constexpr int NC = N / WC / 16;
  __shared__ short8 Ah[4 * 128], Al[4 * 128];
  __shared__ short8 Bh[4 * N], Bl[4 * N];
  const int t = threadIdx.x;
  const int block_row = blockIdx.x * 128;
  const int lane = t & 63, wid = t >> 6;
  const int wr = wid / WC, wc = wid % WC;
  const int rowbase = wr * (128 / WR), colbase = wc * (N / WC);
  const int c = lane >> 4, lr = lane & 15;
  f32x4 acc[MR][NC] = {};
  const int r = t & 127;
  const int grow = block_row + r;
  float nsv = 0.f;
  if (t < 128 && grow < M) nsv = ns[grow];

  for (int k0 = 0; k0 < K; k0 += 32) {
    if (t < 128) {
      f32x4 v[8];
      if (grow < M) {
        const f32x4* ap = (const f32x4*)(A + (size_t)grow * K + k0);
#pragma unroll
        for (int i = 0; i < 8; ++i) v[i] = ap[i] * nsv;
      } else {
#pragma unroll
        for (int i = 0; i < 8; ++i) v[i] = f32x4{0.f, 0.f, 0.f, 0.f};
      }
#pragma unroll
      for (int cc = 0; cc < 4; ++cc) {
        short8 hi, lo;
#pragma unroll
        for (int i = 0; i < 8; ++i) {
          float f = v[cc * 2 + (i >> 2)][i & 3];
          unsigned short h = f2bf(f);
          hi[i] = (short)h;
          lo[i] = (short)f2bf(f - bf2f(h));
        }
        Ah[cc * 128 + r] = hi;
        Al[cc * 128 + r] = lo;
      }
    } else {
      const int tt = t - 128;
#pragma unroll
      for (int id = tt; id < N * 4; id += 128) {
        int col = id & (N - 1);
        int cb = id / N;
        Bh[cb * N + col] = *(const short8*)(Wth + (size_t)col * K + k0 + cb * 8);
        Bl[cb * N + col] = *(const short8*)(Wtl + (size_t)col * K + k0 + cb * 8);
      }
    }
    __syncthreads();
    short8 ah[MR], al[MR], bh[NC], bl[NC];
#pragma unroll
    for (int m = 0; m < MR; ++m) {
      int row = rowbase + m * 16 + lr;
      ah[m] = Ah[c * 128 + row];
      al[m] = Al[c * 128 + row];
    }
#pragma unroll
    for (int n = 0; n < NC; ++n) {
      int col = colbase + n * 16 + lr;
      bh[n] = Bh[c * N + col];
      bl[n] = Bl[c * N + col];
    }
#pragma unroll
    for (int m = 0; m < MR; ++m)
#pragma unroll
      for (int n = 0; n < NC; ++n) {
        acc[m][n] = __builtin_amdgcn_mfma_f32_16x16x32_bf16(ah[m], bh[n], acc[m][n], 0, 0, 0);
        acc[m][n] = __builtin_amdgcn_mfma_f32_16x16x32_bf16(ah[m], bl[n], acc[m][n], 0, 0, 0);
        acc[m][n] = __builtin_amdgcn_mfma_f32_16x16x32_bf16(al[m], bh[n], acc[m][n], 0, 0, 0);
      }
    __syncthreads();
  }
#pragma unroll
  for (int m = 0; m < MR; ++m) {
#pragma unroll
    for (int j = 0; j < 4; ++j) {
      int row = block_row + rowbase + m * 16 + (lane >> 4) * 4 + j;
      if (row < M) {
#pragma unroll
        for (int n = 0; n < NC; ++n)
          C[(size_t)row * N + colbase + n * 16 + lr] = acc[m][n][j];
      }
    }
  }
}

// ---------------- FUSED agg128 + GEMM2: h2 = (relu(nd*agg(h1)+b1) * ns) @ W2 ----------------
// Block = 4 waves = 16 nodes. Each wave gathers 4 nodes' z1 rows (f32x2/lane),
// packs bf16 hi/lo into XOR-swizzled LDS A-tile; then 16x128x64 bf16-split
// mini-GEMM (B-frags of W2 in regs) writes h2 rows directly. No z1 in HBM.
__launch_bounds__(256, 4)
__global__ void k_agg128f(const float* __restrict__ h, const int* __restrict__ offs,
                          const int2* __restrict__ esw, const float* __restrict__ nd,
                          const float* __restrict__ b1v, const float* __restrict__ ns,
                          const short* __restrict__ w2h, const short* __restrict__ w2l,
                          float* __restrict__ h2, int M) {
  __shared__ unsigned Ah32[16 * 64], Al32[16 * 64];
  const int t = threadIdx.x, lane = t & 63, wid = t >> 6;
  const int base = blockIdx.x * 16;
  const f32x2* hp = (const f32x2*)h;
  f32x2 bv = ((const f32x2*)b1v)[lane];
  for (int q = 0; q < 4; ++q) {
    const int row = wid * 4 + q;
    const int node = base + row;
    unsigned hi_pack = 0, lo_pack = 0;
    if (node < M) {
      int s0 = offs[node], s1 = offs[node + 1];
      float a0 = 0.f, a1 = 0.f;
      for (int bb = s0; bb < s1; bb += 64) {
        int kk = bb + lane;
        int sidx = 0;
        float wt = 0.f;
        if (kk < s1) {
          int2 e = esw[kk];
          sidx = e.x;
          wt = __builtin_bit_cast(float, e.y);
        }
        int cnt = min(64, s1 - bb);
        for (int jj = 0; jj < cnt; jj += 16) {
          f32x2 v[16];
          float wu[16];
#pragma unroll
          for (int u = 0; u < 16; ++u) {
            int s = rdlane_i(sidx, jj + u);
            wu[u] = rdlane_f(wt, jj + u);
            v[u] = hp[(size_t)(unsigned)s * 64 + lane];
          }
#pragma unroll
          for (int u = 0; u < 16; ++u) {
            a0 += v[u][0] * wu[u];
            a1 += v[u][1] * wu[u];
          }
        }
      }
      float ndv = nd[node], nsv = ns[node];
      float z0 = fmaxf(a0 * ndv + bv[0], 0.f) * nsv;
      float z1 = fmaxf(a1 * ndv + bv[1], 0.f) * nsv;
      unsigned short h0 = f2bf(z0), h1b = f2bf(z1);
      hi_pack = (unsigned)h0 | ((unsigned)h1b << 16);
      unsigned short l0 = f2bf(z0 - bf2f(h0)), l1 = f2bf(z1 - bf2f(h1b));
      lo_pack = (unsigned)l0 | ((unsigned)l1 << 16);
    }
    int idx = row * 64 + (lane ^ ((row & 7) << 2));  // XOR swizzle (16B blocks)
    Ah32[idx] = hi_pack;
    Al32[idx] = lo_pack;
  }
  __syncthreads();
  // B-frags for this wave's 16-col tile of W2 ([64][128] bf16 planes)
  const int colB = wid * 16 + (lane & 15);
  const int koff = (lane >> 4) * 8;
  short8 bh[4], bl[4];
#pragma unroll
  for (int ks = 0; ks < 4; ++ks) {
    bh[ks] = *(const short8*)(w2h + (size_t)colB * 128 + ks * 32 + koff);
    bl[ks] = *(const short8*)(w2l + (size_t)colB * 128 + ks * 32 + koff);
  }
  const int arow = lane & 15, ac = lane >> 4;
  f32x4 acc = {};
#pragma unroll
  for (int ks = 0; ks < 4; ++ks) {
    int bidx = arow * 64 + ((ks * 16 + ac * 4) ^ ((arow & 7) << 2));
    short8 ah = *(const short8*)(Ah32 + bidx);
    short8 al = *(const short8*)(Al32 + bidx);
    acc = __builtin_amdgcn_mfma_f32_16x16x32_bf16(ah, bh[ks], acc, 0, 0, 0);
    acc = __builtin_amdgcn_mfma_f32_16x16x32_bf16(ah, bl[ks], acc, 0, 0, 0);
    acc = __builtin_amdgcn_mfma_f32_16x16x32_bf16(al, bh[ks], acc, 0, 0, 0);
  }
  const int crow = (lane >> 4) * 4;
  const int col = wid * 16 + (lane & 15);
#pragma unroll
  for (int j = 0; j < 4; ++j) {
    int node = base + crow + j;
    if (node < M) h2[(size_t)node * 64 + col] = acc[j];
  }
}

// ---------------- aggregation D=64 fused with 64->1 matvec ----------------
__global__ void k_agg64mv(const float* __restrict__ h, const int* __restrict__ offs,
                          const int2* __restrict__ esw, const float* __restrict__ nd,
                          const float* __restrict__ b2, const float* __restrict__ W3,
                          const float* __restrict__ ns, float* __restrict__ h3, int M) {
  int w = blockIdx.x * (blockDim.x >> 6) + (threadIdx.x >> 6);
  int lane = threadIdx.x & 63;
  if (w >= M) return;
  int s0 = offs[w], s1 = offs[w + 1];
  float acc = 0.f;
  for (int base = s0; base < s1; base += 64) {
    int kk = base + lane;
    int sidx = 0;
    float wt = 0.f;
    if (kk < s1) {
      int2 e = esw[kk];
      sidx = e.x;
      wt = __builtin_bit_cast(float, e.y);
    }
    int cnt = min(64, s1 - base);
    for (int jj = 0; jj < cnt; jj += 16) {
      float v[16], wu[16];
#pragma unroll
      for (int u = 0; u < 16; ++u) {
        int s = rdlane_i(sidx, jj + u);
        wu[u] = rdlane_f(wt, jj + u);
        v[u] = h[(size_t)(unsigned)s * 64 + lane];
      }
#pragma unroll
      for (int u = 0; u < 16; ++u) acc += v[u] * wu[u];
    }
  }
  float r = fmaxf(acc * nd[w] + b2[lane], 0.f);
  float p = r * W3[lane];
#pragma unroll
  for (int d = 32; d; d >>= 1) p += __shfl_xor(p, d);
  if (lane == 0) h3[w] = p * ns[w];
}

// ---------------- final scalar aggregation ----------------
__global__ void k_aggfin(const float* __restrict__ h3, const int* __restrict__ offs,
                         const int2* __restrict__ esw, const float* __restrict__ nd,
                         const float* __restrict__ b3, float* __restrict__ out, int M) {
  int i = blockIdx.x * blockDim.x + threadIdx.x;
  if (i >= M) return;
  int s0 = offs[i], s1 = offs[i + 1];
  float acc = 0.f;
  int k = s0;
  for (; k + 4 <= s1; k += 4) {
    int2 e0 = esw[k], e1 = esw[k + 1], e2 = esw[k + 2], e3 = esw[k + 3];
    acc += h3[e0.x] * __builtin_bit_cast(float, e0.y)
         + h3[e1.x] * __builtin_bit_cast(float, e1.y)
         + h3[e2.x] * __builtin_bit_cast(float, e2.y)
         + h3[e3.x] * __builtin_bit_cast(float, e3.y);
  }
  for (; k < s1; ++k) {
    int2 e = esw[k];
    acc += h3[e.x] * __builtin_bit_cast(float, e.y);
  }
  out[i] = acc * nd[i] + b3[0];
}

extern "C" void kernel_launch(void* const* d_in, const int* in_sizes, int n_in,
                              void* d_out, int out_size, void* d_ws, size_t ws_size,
                              hipStream_t stream) {
  const float* b_z = (const float*)d_in[0];
  const int*   src = (const int*)d_in[1];
  const int*   dst = (const int*)d_in[2];
  const float* ew  = (const float*)d_in[3];
  const float* W1  = (const float*)d_in[5];
  const float* b1  = (const float*)d_in[6];
  const float* W2  = (const float*)d_in[7];
  const float* b2  = (const float*)d_in[8];
  const float* W3  = (const float*)d_in[9];
  const float* b3  = (const float*)d_in[10];
  const int N = in_sizes[0] / D0;
  const int E = in_sizes[1];
  float* out = (float*)d_out;

  char* ws = (char*)d_ws;
  size_t off_b = 0;
  auto alloc = [&](size_t bytes) -> void* {
    void* p = ws + off_b;
    off_b += (bytes + 255) & ~(size_t)255;
    return p;
  };
  const int nbk = (E + EBLK - 1) / EBLK;
  int*   bc_s    = (int*)alloc((size_t)nbk * NB * 4);
  int*   bc_d    = (int*)alloc((size_t)nbk * NB * 4);
  int*   bt_s    = (int*)alloc((size_t)NB * 4);
  int*   bt_d    = (int*)alloc((size_t)NB * 4);
  int*   cbase_s = (int*)alloc((size_t)(NB + 1) * 4);
  int*   cbase_d = (int*)alloc((size_t)(NB + 1) * 4);
  int*   offs    = (int*)alloc((size_t)(N + 1) * 4);
  int2*  esw     = (int2*)alloc((size_t)E * 8);
  float* nsrc    = (float*)alloc((size_t)N * 4);
  float* ndst    = (float*)alloc((size_t)N * 4);
  float* h1      = (float*)alloc((size_t)N * D1 * 4);  // 51.2 MB
  float* h2      = (float*)alloc((size_t)N * D2 * 4);  // 25.6 MB (read h1 while writing -> no alias)
  float* h3      = (float*)alloc((size_t)N * 4);
  short* wt1h    = (short*)alloc((size_t)D0 * D1 * 2);
  short* wt1l    = (short*)alloc((size_t)D0 * D1 * 2);
  short* wt2h    = (short*)alloc((size_t)D1 * D2 * 2);
  short* wt2l    = (short*)alloc((size_t)D1 * D2 * 2);
  // partition records alias h1 (both dead before GEMM1 writes h1)
  int2*  recs_d = (int2*)h1;                              // E*8 = 12.8 MB
  int*   recs_s = (int*)((char*)h1 + ((size_t)16 << 20)); // E*4 = 6.4 MB @ +16MB

  // --- CSR build (atomic-free, fully parallel) ---
  k_chist2<<<nbk, 256, 0, stream>>>(src, dst, bc_s, bc_d, E);
  k_binscan<<<dim3(NB, 2), 256, 0, stream>>>(bc_s, bt_s, bc_d, bt_d, nbk);
  k_btscan<<<2, 1024, 0, stream>>>(bt_s, cbase_s, bt_d, cbase_d, &offs[N], E);
  k_cpart2<<<nbk, 256, 0, stream>>>(src, dst, ew, bc_s, cbase_s, bc_d, cbase_d,
                                    recs_s, recs_d, E);
  k_fineh<<<NB, 256, 0, stream>>>(recs_s, cbase_s, nsrc, N);
  k_fine<<<NB, 256, 0, stream>>>(recs_d, cbase_d, esw, offs, ndst, N);

  k_wsplit<<<(D0 * D1 + 255) / 256, 256, 0, stream>>>(W1, wt1h, wt1l, D0, D1);
  k_wsplit<<<(D1 * D2 + 255) / 256, 256, 0, stream>>>(W2, wt2h, wt2l, D1, D2);

  // layer 1: 256 -> 128 (MFMA)
  k_gemm_mfma<D0, D1, 2, 2><<<(N + 127) / 128, 256, 0, stream>>>(b_z, nsrc, wt1h, wt1l, h1, N);
  // layer-1 agg + layer-2 projection fused (writes h2 directly, no z1)
  k_agg128f<<<(N + 15) / 16, 256, 0, stream>>>(h1, offs, esw, ndst, b1, nsrc,
                                               wt2h, wt2l, h2, N);
  // layer-2 agg fused with layer-3 projection (64->1 matvec)
  k_agg64mv<<<(N + 3) / 4, 256, 0, stream>>>(h2, offs, esw, ndst, b2, W3, nsrc, h3, N);
  // final scalar aggregation
  k_aggfin<<<(N + 255) / 256, 256, 0, stream>>>(h3, offs, esw, ndst, b3, out, N);
}

// Round 9
// 328.338 us; speedup vs baseline: 2.3166x; 1.0138x over previous
//
#include <hip/hip_runtime.h>

// GCN decoder. Atomic-free CSR build (two-level counting sort) ->
// GEMM1(MFMA bf16-split) -> agg128 FUSED with GEMM2 (LDS mini-GEMM epilogue) ->
// agg64+matvec(W3) -> final scalar agg.
// Round 9: sched_barrier-forced gather MLP + node-pipelined agg kernels +
// coalesced binscan.

constexpr int D0 = 256, D1 = 128, D2 = 64;
constexpr int NB = 1024;   // coarse bins
constexpr int BSH = 7;     // bin = key >> 7 (128 nodes per bin)
constexpr int EBLK = 4096; // edges per block in hist/partition kernels

typedef __attribute__((ext_vector_type(2))) float f32x2;
typedef __attribute__((ext_vector_type(4))) float f32x4;
typedef __attribute__((ext_vector_type(8))) short short8;

__device__ inline unsigned short f2bf(float f) {
  unsigned u = __builtin_bit_cast(unsigned, f);
  u += 0x7fffu + ((u >> 16) & 1u);
  return (unsigned short)(u >> 16);
}
__device__ inline float bf2f(unsigned short h) {
  unsigned u = ((unsigned)h) << 16;
  return __builtin_bit_cast(float, u);
}
__device__ inline int rdlane_i(int v, int l) { return __builtin_amdgcn_readlane(v, l); }
__device__ inline float rdlane_f(float v, int l) {
  return __builtin_bit_cast(float, __builtin_amdgcn_readlane(__builtin_bit_cast(int, v), l));
}

// ---------------- merged coarse histograms: src and dst in one edge pass ----------------
__global__ void k_chist2(const int* __restrict__ src, const int* __restrict__ dst,
                         int* __restrict__ bc_s, int* __restrict__ bc_d, int E) {
  __shared__ int hs[NB], hd[NB];
  for (int i = threadIdx.x; i < NB; i += 256) { hs[i] = 0; hd[i] = 0; }
  __syncthreads();
  int e0 = blockIdx.x * EBLK, e1 = min(e0 + EBLK, E);
  for (int i = e0 + threadIdx.x; i < e1; i += 256) {
    atomicAdd(&hs[src[i] >> BSH], 1);
    atomicAdd(&hd[dst[i] >> BSH], 1);
  }
  __syncthreads();
  for (int i = threadIdx.x; i < NB; i += 256) {
    bc_s[blockIdx.x * NB + i] = hs[i];
    bc_d[blockIdx.x * NB + i] = hd[i];
  }
}

// ---------------- coalesced column scan: block = 16 consecutive bins ----------------
// threads (c,j): chunk c of blocks, bin j in tile -> 64B-line-coalesced reads.
__global__ void k_binscan(int* __restrict__ bc_s, int* __restrict__ bt_s,
                          int* __restrict__ bc_d, int* __restrict__ bt_d, int nbk) {
  __shared__ int part[16][17];
  int* bc = blockIdx.y ? bc_d : bc_s;
  int* bt = blockIdx.y ? bt_d : bt_s;
  const int j = threadIdx.x & 15;   // bin within tile
  const int c = threadIdx.x >> 4;   // chunk 0..15
  const int bin = blockIdx.x * 16 + j;
  const int chunk = (nbk + 15) / 16;
  const int r0 = c * chunk, r1 = min(r0 + chunk, nbk);
  int s = 0;
  for (int b = r0; b < r1; ++b) s += bc[b * NB + bin];
  part[c][j] = s;
  __syncthreads();
  int pre = 0;
  for (int q = 0; q < c; ++q) pre += part[q][j];
  int run = pre;
  for (int b = r0; b < r1; ++b) {
    int v = bc[b * NB + bin];
    bc[b * NB + bin] = run;
    run += v;
  }
  if (c == 15) bt[bin] = run;  // grand total of this bin
}

// ---------------- scan of 1024 bin totals (block 0: src, block 1: dst) ----------------
__global__ void k_btscan(const int* __restrict__ bt_s, int* __restrict__ cbase_s,
                         const int* __restrict__ bt_d, int* __restrict__ cbase_d,
                         int* __restrict__ offs_end, int E) {
  __shared__ int wsum[16];
  const int* bt = blockIdx.x ? bt_d : bt_s;
  int* cbase = blockIdx.x ? cbase_d : cbase_s;
  int tid = threadIdx.x, lane = tid & 63, wid = tid >> 6;
  int v = bt[tid];
  int x = v;
#pragma unroll
  for (int d = 1; d < 64; d <<= 1) { int t = __shfl_up(x, d); if (lane >= d) x += t; }
  if (lane == 63) wsum[wid] = x;
  __syncthreads();
  if (wid == 0 && lane < 16) {
    int s = wsum[lane];
#pragma unroll
    for (int d = 1; d < 16; d <<= 1) { int t = __shfl_up(s, d, 16); if (lane >= d) s += t; }
    wsum[lane] = s;
  }
  __syncthreads();
  int excl = x - v + (wid ? wsum[wid - 1] : 0);
  cbase[tid] = excl;
  if (tid == NB - 1) cbase[NB] = E;
  if (blockIdx.x == 1 && tid == 0) *offs_end = E;
}

// ---------------- merged coarse partition: one edge pass, both sides ----------------
__global__ void k_cpart2(const int* __restrict__ src, const int* __restrict__ dst,
                         const float* __restrict__ ew,
                         const int* __restrict__ bc_s, const int* __restrict__ cbase_s,
                         const int* __restrict__ bc_d, const int* __restrict__ cbase_d,
                         int* __restrict__ recs_s, int2* __restrict__ recs_d, int E) {
  __shared__ int cs[NB], cd[NB];
  for (int i = threadIdx.x; i < NB; i += 256) {
    cs[i] = cbase_s[i] + bc_s[blockIdx.x * NB + i];
    cd[i] = cbase_d[i] + bc_d[blockIdx.x * NB + i];
  }
  __syncthreads();
  int e0 = blockIdx.x * EBLK, e1 = min(e0 + EBLK, E);
  for (int i = e0 + threadIdx.x; i < e1; i += 256) {
    int s = src[i], d = dst[i];
    int ps = atomicAdd(&cs[s >> BSH], 1);
    recs_s[ps] = s;
    int pd = atomicAdd(&cd[d >> BSH], 1);
    recs_d[pd] = int2{s | ((d & 127) << 17), __builtin_bit_cast(int, ew[i])};
  }
}

// ---------------- fine CSR per coarse bin: offs, nd, ordered esw ----------------
__global__ void k_fine(const int2* __restrict__ recs, const int* __restrict__ cbase,
                       int2* __restrict__ esw, int* __restrict__ offs,
                       float* __restrict__ nd, int N) {
  __shared__ int h[128], cur[128];
  __shared__ int w0tot;
  int bin = blockIdx.x;
  int r0 = cbase[bin], r1 = cbase[bin + 1];
  int t = threadIdx.x;
  if (t < 128) h[t] = 0;
  __syncthreads();
  for (int i = r0 + t; i < r1; i += 256) atomicAdd(&h[recs[i].x >> 17], 1);
  __syncthreads();
  int v = 0, x = 0;
  if (t < 128) {
    v = h[t];
    x = v;
#pragma unroll
    for (int d = 1; d < 64; d <<= 1) { int tt = __shfl_up(x, d); if ((t & 63) >= d) x += tt; }
    if (t == 63) w0tot = x;
  }
  __syncthreads();
  if (t < 128) {
    int excl = x - v + (t >= 64 ? w0tot : 0);
    int node = bin * 128 + t;
    if (node < N) {
      offs[node] = r0 + excl;
      int d = v < 1 ? 1 : v;
      nd[node] = (float)(1.0 / sqrt((double)d));
    }
    cur[t] = r0 + excl;
  }
  __syncthreads();
  for (int i = r0 + t; i < r1; i += 256) {
    int2 rc = recs[i];
    int p = atomicAdd(&cur[rc.x >> 17], 1);
    esw[p] = int2{rc.x & 0x1ffff, rc.y};
  }
}

// ---------------- fine histogram per coarse bin (src side): ns only ----------------
__global__ void k_fineh(const int* __restrict__ recs, const int* __restrict__ cbase,
                        float* __restrict__ ns, int N) {
  __shared__ int h[128];
  int bin = blockIdx.x;
  int r0 = cbase[bin], r1 = cbase[bin + 1];
  int t = threadIdx.x;
  if (t < 128) h[t] = 0;
  __syncthreads();
  for (int i = r0 + t; i < r1; i += 256) atomicAdd(&h[recs[i] & 127], 1);
  __syncthreads();
  if (t < 128) {
    int node = bin * 128 + t;
    if (node < N) {
      int d = h[t] < 1 ? 1 : h[t];
      ns[node] = (float)(1.0 / sqrt((double)d));
    }
  }
}

// ---------------- W split: W[K][N] fp32 -> Wt_hi/Wt_lo [N][K] bf16 ----------------
__global__ void k_wsplit(const float* __restrict__ W, short* __restrict__ hi,
                         short* __restrict__ lo, int K, int N) {
  int t = blockIdx.x * blockDim.x + threadIdx.x;
  if (t < K * N) {
    int k = t / N, n = t % N;
    float f = W[t];
    unsigned short h = f2bf(f);
    hi[(size_t)n * K + k] = (short)h;
    lo[(size_t)n * K + k] = (short)f2bf(f - bf2f(h));
  }
}

// ---------------- MFMA GEMM (layer 1): C[M,N] = (A * ns[:,None]) @ W ----------------
template <int K, int N, int WR, int WC>
__launch_bounds__(256, 2)
__global__ void k_gemm_mfma(const float* __restrict__ A, const float* __restrict__ ns,
                            const short* __restrict__ Wth, const short* __restrict__ Wtl,
                            float* __restrict__ C, int M) {
  constexpr int MR = 128 / WR / 16;
  constexpr int NC = N / WC / 16;
  __shared__ short8 Ah[4 * 128], Al[4 * 128];
  __shared__ short8 Bh[4 * N], Bl[4 * N];
  const int t = threadIdx.x;
  const int block_row = blockIdx.x * 128;
  const int lane = t & 63, wid = t >> 6;
  const int wr = wid / WC, wc = wid % WC;
  const int rowbase = wr * (128 / WR), colbase = wc * (N / WC);
  const int c = lane >> 4, lr = lane & 15;
  f32x4 acc[MR][NC] = {};
  const int r = t & 127;
  const int grow = block_row + r;
  float nsv = 0.f;
  if (t < 128 && grow < M) nsv = ns[grow];

  for (int k0 = 0; k0 < K; k0 += 32) {
    if (t < 128) {
      f32x4 v[8];
      if (grow < M) {
        const f32x4* ap = (const f32x4*)(A + (size_t)grow * K + k0);
#pragma unroll
        for (int i = 0; i < 8; ++i) v[i] = ap[i] * nsv;
      } else {
#pragma unroll
        for (int i = 0; i < 8; ++i) v[i] = f32x4{0.f, 0.f, 0.f, 0.f};
      }
#pragma unroll
      for (int cc = 0; cc < 4; ++cc) {
        short8 hi, lo;
#pragma unroll
        for (int i = 0; i < 8; ++i) {
          float f = v[cc * 2 + (i >> 2)][i & 3];
          unsigned short h = f2bf(f);
          hi[i] = (short)h;
          lo[i] = (short)f2bf(f - bf2f(h));
        }
        Ah[cc * 128 + r] = hi;
        Al[cc * 128 + r] = lo;
      }
    } else {
      const int tt = t - 128;
#pragma unroll
      for (int id = tt; id < N * 4; id += 128) {
        int col = id & (N - 1);
        int cb = id / N;
        Bh[cb * N + col] = *(const short8*)(Wth + (size_t)col * K + k0 + cb * 8);
        Bl[cb * N + col] = *(const short8*)(Wtl + (size_t)col * K + k0 + cb * 8);
      }
    }
    __syncthreads();
    short8 ah[MR], al[MR], bh[NC], bl[NC];
#pragma unroll
    for (int m = 0; m < MR; ++m) {
      int row = rowbase + m * 16 + lr;
      ah[m] = Ah[c * 128 + row];
      al[m] = Al[c * 128 + row];
    }
#pragma unroll
    for (int n = 0; n < NC; ++n) {
      int col = colbase + n * 16 + lr;
      bh[n] = Bh[c * N + col];
      bl[n] = Bl[c * N + col];
    }
#pragma unroll
    for (int m = 0; m < MR; ++m)
#pragma unroll
      for (int n = 0; n < NC; ++n) {
        acc[m][n] = __builtin_amdgcn_mfma_f32_16x16x32_bf16(ah[m], bh[n], acc[m][n], 0, 0, 0);
        acc[m][n] = __builtin_amdgcn_mfma_f32_16x16x32_bf16(ah[m], bl[n], acc[m][n], 0, 0, 0);
        acc[m][n] = __builtin_amdgcn_mfma_f32_16x16x32_bf16(al[m], bh[n], acc[m][n], 0, 0, 0);
      }
    __syncthreads();
  }
#pragma unroll
  for (int m = 0; m < MR; ++m) {
#pragma unroll
    for (int j = 0; j < 4; ++j) {
      int row = block_row + rowbase + m * 16 + (lane >> 4) * 4 + j;
      if (row < M) {
#pragma unroll
        for (int n = 0; n < NC; ++n)
          C[(size_t)row * N + colbase + n * 16 + lr] = acc[m][n][j];
      }
    }
  }
}

// ---------------- FUSED agg128 + GEMM2, node-pipelined, forced-MLP gathers ----------------
__launch_bounds__(256, 4)
__global__ void k_agg128f(const float* __restrict__ h, const int* __restrict__ offs,
                          const int2* __restrict__ esw, const float* __restrict__ nd,
                          const float* __restrict__ b1v, const float* __restrict__ ns,
                          const short* __restrict__ w2h, const short* __restrict__ w2l,
                          float* __restrict__ h2, int M) {
  __shared__ unsigned Ah32[16 * 64], Al32[16 * 64];
  const int t = threadIdx.x, lane = t & 63, wid = t >> 6;
  const int base = blockIdx.x * 16;
  const int nb0 = base + wid * 4;
  const f32x2* hp = (const f32x2*)h;
  f32x2 bv = ((const f32x2*)b1v)[lane];
  // batch-load offs[nb0..nb0+4] via lanes 0..4, broadcast
  int ov = offs[min(nb0 + min(lane, 5), M)];
  int S0[4], S1[4];
#pragma unroll
  for (int q = 0; q < 4; ++q) { S0[q] = rdlane_i(ov, q); S1[q] = rdlane_i(ov, q + 1); }
  // prefetch node 0's first edge-meta chunk
  int2 ecur{0, 0};
  { int kk = S0[0] + lane; if (kk < S1[0]) ecur = esw[kk]; }
#pragma unroll
  for (int q = 0; q < 4; ++q) {
    const int row = wid * 4 + q;
    const int node = nb0 + q;
    int2 enxt{0, 0};
    if (q < 3) { int kk = S0[q + 1] + lane; if (kk < S1[q + 1]) enxt = esw[kk]; }
    unsigned hi_pack = 0, lo_pack = 0;
    if (node < M) {
      const int s0 = S0[q], s1 = S1[q];
      float a0 = 0.f, a1 = 0.f;
      int2 e = ecur;
      for (int bb = s0; bb < s1; bb += 64) {
        if (bb != s0) { int kk = bb + lane; e = (kk < s1) ? esw[kk] : int2{0, 0}; }
        int sidx = e.x;
        float wt = __builtin_bit_cast(float, e.y);
        int cnt = min(64, s1 - bb);
        for (int jj = 0; jj < cnt; jj += 16) {
          f32x2 v[16];
#pragma unroll
          for (int u = 0; u < 16; ++u) {
            int s = rdlane_i(sidx, jj + u);
            v[u] = hp[(size_t)(unsigned)s * 64 + lane];
          }
          __builtin_amdgcn_sched_barrier(0);  // keep all 16 gathers in flight
#pragma unroll
          for (int u = 0; u < 16; ++u) {
            float wu = rdlane_f(wt, jj + u);
            a0 += v[u][0] * wu;
            a1 += v[u][1] * wu;
          }
        }
      }
      float ndv = nd[node], nsv = ns[node];
      float z0 = fmaxf(a0 * ndv + bv[0], 0.f) * nsv;
      float z1 = fmaxf(a1 * ndv + bv[1], 0.f) * nsv;
      unsigned short h0 = f2bf(z0), h1b = f2bf(z1);
      hi_pack = (unsigned)h0 | ((unsigned)h1b << 16);
      unsigned short l0 = f2bf(z0 - bf2f(h0)), l1 = f2bf(z1 - bf2f(h1b));
      lo_pack = (unsigned)l0 | ((unsigned)l1 << 16);
    }
    int idx = row * 64 + (lane ^ ((row & 7) << 2));  // XOR swizzle (16B blocks)
    Ah32[idx] = hi_pack;
    Al32[idx] = lo_pack;
    ecur = enxt;
  }
  __syncthreads();
  // B-frags for this wave's 16-col tile of W2 ([64][128] bf16 planes)
  const int colB = wid * 16 + (lane & 15);
  const int koff = (lane >> 4) * 8;
  short8 bh[4], bl[4];
#pragma unroll
  for (int ks = 0; ks < 4; ++ks) {
    bh[ks] = *(const short8*)(w2h + (size_t)colB * 128 + ks * 32 + koff);
    bl[ks] = *(const short8*)(w2l + (size_t)colB * 128 + ks * 32 + koff);
  }
  const int arow = lane & 15, ac = lane >> 4;
  f32x4 acc = {};
#pragma unroll
  for (int ks = 0; ks < 4; ++ks) {
    int bidx = arow * 64 + ((ks * 16 + ac * 4) ^ ((arow & 7) << 2));
    short8 ah = *(const short8*)(Ah32 + bidx);
    short8 al = *(const short8*)(Al32 + bidx);
    acc = __builtin_amdgcn_mfma_f32_16x16x32_bf16(ah, bh[ks], acc, 0, 0, 0);
    acc = __builtin_amdgcn_mfma_f32_16x16x32_bf16(ah, bl[ks], acc, 0, 0, 0);
    acc = __builtin_amdgcn_mfma_f32_16x16x32_bf16(al, bh[ks], acc, 0, 0, 0);
  }
  const int crow = (lane >> 4) * 4;
  const int col = wid * 16 + (lane & 15);
#pragma unroll
  for (int j = 0; j < 4; ++j) {
    int node = base + crow + j;
    if (node < M) h2[(size_t)node * 64 + col] = acc[j];
  }
}

// ---------------- agg64+matvec: node-pipelined (4 nodes/wave), forced-MLP ----------------
__global__ void k_agg64mv(const float* __restrict__ h, const int* __restrict__ offs,
                          const int2* __restrict__ esw, const float* __restrict__ nd,
                          const float* __restrict__ b2, const float* __restrict__ W3,
                          const float* __restrict__ ns, float* __restrict__ h3, int M) {
  const int lane = threadIdx.x & 63;
  const int wave = blockIdx.x * (blockDim.x >> 6) + (threadIdx.x >> 6);
  const int nb0 = wave * 4;
  if (nb0 >= M) return;
  int ov = offs[min(nb0 + min(lane, 5), M)];
  int S0[4], S1[4];
#pragma unroll
  for (int q = 0; q < 4; ++q) { S0[q] = rdlane_i(ov, q); S1[q] = rdlane_i(ov, q + 1); }
  float bv = b2[lane], w3 = W3[lane];
  int2 ecur{0, 0};
  { int kk = S0[0] + lane; if (kk < S1[0]) ecur = esw[kk]; }
#pragma unroll
  for (int q = 0; q < 4; ++q) {
    const int node = nb0 + q;
    int2 enxt{0, 0};
    if (q < 3) { int kk = S0[q + 1] + lane; if (kk < S1[q + 1]) enxt = esw[kk]; }
    if (node < M) {
      const int s0 = S0[q], s1 = S1[q];
      float acc = 0.f;
      int2 e = ecur;
      for (int bb = s0; bb < s1; bb += 64) {
        if (bb != s0) { int kk = bb + lane; e = (kk < s1) ? esw[kk] : int2{0, 0}; }
        int sidx = e.x;
        float wt = __builtin_bit_cast(float, e.y);
        int cnt = min(64, s1 - bb);
        for (int jj = 0; jj < cnt; jj += 16) {
          float v[16];
#pragma unroll
          for (int u = 0; u < 16; ++u) {
            int s = rdlane_i(sidx, jj + u);
            v[u] = h[(size_t)(unsigned)s * 64 + lane];
          }
          __builtin_amdgcn_sched_barrier(0);  // keep all 16 gathers in flight
#pragma unroll
          for (int u = 0; u < 16; ++u) acc += v[u] * rdlane_f(wt, jj + u);
        }
      }
      float r = fmaxf(acc * nd[node] + bv, 0.f);
      float p = r * w3;
#pragma unroll
      for (int d = 32; d; d >>= 1) p += __shfl_xor(p, d);
      if (lane == 0) h3[node] = p * ns[node];
    }
    ecur = enxt;
  }
}

// ---------------- final scalar aggregation ----------------
__global__ void k_aggfin(const float* __restrict__ h3, const int* __restrict__ offs,
                         const int2* __restrict__ esw, const float* __restrict__ nd,
                         const float* __restrict__ b3, float* __restrict__ out, int M) {
  int i = blockIdx.x * blockDim.x + threadIdx.x;
  if (i >= M) return;
  int s0 = offs[i], s1 = offs[i + 1];
  float acc = 0.f;
  int k = s0;
  for (; k + 4 <= s1; k += 4) {
    int2 e0 = esw[k], e1 = esw[k + 1], e2 = esw[k + 2], e3 = esw[k + 3];
    acc += h3[e0.x] * __builtin_bit_cast(float, e0.y)
         + h3[e1.x] * __builtin_bit_cast(float, e1.y)
         + h3[e2.x] * __builtin_bit_cast(float, e2.y)
         + h3[e3.x] * __builtin_bit_cast(float, e3.y);
  }
  for (; k < s1; ++k) {
    int2 e = esw[k];
    acc += h3[e.x] * __builtin_bit_cast(float, e.y);
  }
  out[i] = acc * nd[i] + b3[0];
}

extern "C" void kernel_launch(void* const* d_in, const int* in_sizes, int n_in,
                              void* d_out, int out_size, void* d_ws, size_t ws_size,
                              hipStream_t stream) {
  const float* b_z = (const float*)d_in[0];
  const int*   src = (const int*)d_in[1];
  const int*   dst = (const int*)d_in[2];
  const float* ew  = (const float*)d_in[3];
  const float* W1  = (const float*)d_in[5];
  const float* b1  = (const float*)d_in[6];
  const float* W2  = (const float*)d_in[7];
  const float* b2  = (const float*)d_in[8];
  const float* W3  = (const float*)d_in[9];
  const float* b3  = (const float*)d_in[10];
  const int N = in_sizes[0] / D0;
  const int E = in_sizes[1];
  float* out = (float*)d_out;

  char* ws = (char*)d_ws;
  size_t off_b = 0;
  auto alloc = [&](size_t bytes) -> void* {
    void* p = ws + off_b;
    off_b += (bytes + 255) & ~(size_t)255;
    return p;
  };
  const int nbk = (E + EBLK - 1) / EBLK;
  int*   bc_s    = (int*)alloc((size_t)nbk * NB * 4);
  int*   bc_d    = (int*)alloc((size_t)nbk * NB * 4);
  int*   bt_s    = (int*)alloc((size_t)NB * 4);
  int*   bt_d    = (int*)alloc((size_t)NB * 4);
  int*   cbase_s = (int*)alloc((size_t)(NB + 1) * 4);
  int*   cbase_d = (int*)alloc((size_t)(NB + 1) * 4);
  int*   offs    = (int*)alloc((size_t)(N + 1) * 4);
  int2*  esw     = (int2*)alloc((size_t)E * 8);
  float* nsrc    = (float*)alloc((size_t)N * 4);
  float* ndst    = (float*)alloc((size_t)N * 4);
  float* h1      = (float*)alloc((size_t)N * D1 * 4);  // 51.2 MB
  float* h2      = (float*)alloc((size_t)N * D2 * 4);  // 25.6 MB
  float* h3      = (float*)alloc((size_t)N * 4);
  short* wt1h    = (short*)alloc((size_t)D0 * D1 * 2);
  short* wt1l    = (short*)alloc((size_t)D0 * D1 * 2);
  short* wt2h    = (short*)alloc((size_t)D1 * D2 * 2);
  short* wt2l    = (short*)alloc((size_t)D1 * D2 * 2);
  // partition records alias h1 (both dead before GEMM1 writes h1)
  int2*  recs_d = (int2*)h1;                              // E*8 = 12.8 MB
  int*   recs_s = (int*)((char*)h1 + ((size_t)16 << 20)); // E*4 = 6.4 MB @ +16MB

  // --- CSR build (atomic-free, fully parallel) ---
  k_chist2<<<nbk, 256, 0, stream>>>(src, dst, bc_s, bc_d, E);
  k_binscan<<<dim3(NB / 16, 2), 256, 0, stream>>>(bc_s, bt_s, bc_d, bt_d, nbk);
  k_btscan<<<2, 1024, 0, stream>>>(bt_s, cbase_s, bt_d, cbase_d, &offs[N], E);
  k_cpart2<<<nbk, 256, 0, stream>>>(src, dst, ew, bc_s, cbase_s, bc_d, cbase_d,
                                    recs_s, recs_d, E);
  k_fineh<<<NB, 256, 0, stream>>>(recs_s, cbase_s, nsrc, N);
  k_fine<<<NB, 256, 0, stream>>>(recs_d, cbase_d, esw, offs, ndst, N);

  k_wsplit<<<(D0 * D1 + 255) / 256, 256, 0, stream>>>(W1, wt1h, wt1l, D0, D1);
  k_wsplit<<<(D1 * D2 + 255) / 256, 256, 0, stream>>>(W2, wt2h, wt2l, D1, D2);

  // layer 1: 256 -> 128 (MFMA)
  k_gemm_mfma<D0, D1, 2, 2><<<(N + 127) / 128, 256, 0, stream>>>(b_z, nsrc, wt1h, wt1l, h1, N);
  // layer-1 agg + layer-2 projection fused (writes h2 directly, no z1)
  k_agg128f<<<(N + 15) / 16, 256, 0, stream>>>(h1, offs, esw, ndst, b1, nsrc,
                                               wt2h, wt2l, h2, N);
  // layer-2 agg fused with layer-3 projection (64->1 matvec)
  k_agg64mv<<<(N + 15) / 16, 256, 0, stream>>>(h2, offs, esw, ndst, b2, W3, nsrc, h3, N);
  // final scalar aggregation
  k_aggfin<<<(N + 255) / 256, 256, 0, stream>>>(h3, offs, esw, ndst, b3, out, N);
}

// Round 10
// 323.833 us; speedup vs baseline: 2.3489x; 1.0139x over previous
//
#include <hip/hip_runtime.h>

// GCN decoder. Atomic-free CSR build (two-level counting sort) ->
// GEMM1(MFMA bf16-split) -> agg128 FUSED with GEMM2 (LDS mini-GEMM epilogue) ->
// agg64+matvec(W3) -> final scalar agg.
// Round 10: dwordx4 gathers (2 edges/wave-load in agg128f, 4 in agg64mv) to
// halve/quarter fabric request count; merged fine+fineh; merged wsplit.

constexpr int D0 = 256, D1 = 128, D2 = 64;
constexpr int NB = 1024;   // coarse bins
constexpr int BSH = 7;     // bin = key >> 7 (128 nodes per bin)
constexpr int EBLK = 4096; // edges per block in hist/partition kernels

typedef __attribute__((ext_vector_type(2))) float f32x2;
typedef __attribute__((ext_vector_type(4))) float f32x4;
typedef __attribute__((ext_vector_type(8))) short short8;

__device__ inline unsigned short f2bf(float f) {
  unsigned u = __builtin_bit_cast(unsigned, f);
  u += 0x7fffu + ((u >> 16) & 1u);
  return (unsigned short)(u >> 16);
}
__device__ inline float bf2f(unsigned short h) {
  unsigned u = ((unsigned)h) << 16;
  return __builtin_bit_cast(float, u);
}
__device__ inline int rdlane_i(int v, int l) { return __builtin_amdgcn_readlane(v, l); }
__device__ inline float rdlane_f(float v, int l) {
  return __builtin_bit_cast(float, __builtin_amdgcn_readlane(__builtin_bit_cast(int, v), l));
}

// ---------------- merged coarse histograms: src and dst in one edge pass ----------------
__global__ void k_chist2(const int* __restrict__ src, const int* __restrict__ dst,
                         int* __restrict__ bc_s, int* __restrict__ bc_d, int E) {
  __shared__ int hs[NB], hd[NB];
  for (int i = threadIdx.x; i < NB; i += 256) { hs[i] = 0; hd[i] = 0; }
  __syncthreads();
  int e0 = blockIdx.x * EBLK, e1 = min(e0 + EBLK, E);
  for (int i = e0 + threadIdx.x; i < e1; i += 256) {
    atomicAdd(&hs[src[i] >> BSH], 1);
    atomicAdd(&hd[dst[i] >> BSH], 1);
  }
  __syncthreads();
  for (int i = threadIdx.x; i < NB; i += 256) {
    bc_s[blockIdx.x * NB + i] = hs[i];
    bc_d[blockIdx.x * NB + i] = hd[i];
  }
}

// ---------------- coalesced column scan: block = 16 consecutive bins ----------------
__global__ void k_binscan(int* __restrict__ bc_s, int* __restrict__ bt_s,
                          int* __restrict__ bc_d, int* __restrict__ bt_d, int nbk) {
  __shared__ int part[16][17];
  int* bc = blockIdx.y ? bc_d : bc_s;
  int* bt = blockIdx.y ? bt_d : bt_s;
  const int j = threadIdx.x & 15;
  const int c = threadIdx.x >> 4;
  const int bin = blockIdx.x * 16 + j;
  const int chunk = (nbk + 15) / 16;
  const int r0 = c * chunk, r1 = min(r0 + chunk, nbk);
  int s = 0;
  for (int b = r0; b < r1; ++b) s += bc[b * NB + bin];
  part[c][j] = s;
  __syncthreads();
  int pre = 0;
  for (int q = 0; q < c; ++q) pre += part[q][j];
  int run = pre;
  for (int b = r0; b < r1; ++b) {
    int v = bc[b * NB + bin];
    bc[b * NB + bin] = run;
    run += v;
  }
  if (c == 15) bt[bin] = run;
}

// ---------------- scan of 1024 bin totals (block 0: src, block 1: dst) ----------------
__global__ void k_btscan(const int* __restrict__ bt_s, int* __restrict__ cbase_s,
                         const int* __restrict__ bt_d, int* __restrict__ cbase_d,
                         int* __restrict__ offs_end, int E) {
  __shared__ int wsum[16];
  const int* bt = blockIdx.x ? bt_d : bt_s;
  int* cbase = blockIdx.x ? cbase_d : cbase_s;
  int tid = threadIdx.x, lane = tid & 63, wid = tid >> 6;
  int v = bt[tid];
  int x = v;
#pragma unroll
  for (int d = 1; d < 64; d <<= 1) { int t = __shfl_up(x, d); if (lane >= d) x += t; }
  if (lane == 63) wsum[wid] = x;
  __syncthreads();
  if (wid == 0 && lane < 16) {
    int s = wsum[lane];
#pragma unroll
    for (int d = 1; d < 16; d <<= 1) { int t = __shfl_up(s, d, 16); if (lane >= d) s += t; }
    wsum[lane] = s;
  }
  __syncthreads();
  int excl = x - v + (wid ? wsum[wid - 1] : 0);
  cbase[tid] = excl;
  if (tid == NB - 1) cbase[NB] = E;
  if (blockIdx.x == 1 && tid == 0) *offs_end = E;
}

// ---------------- merged coarse partition: one edge pass, both sides ----------------
__global__ void k_cpart2(const int* __restrict__ src, const int* __restrict__ dst,
                         const float* __restrict__ ew,
                         const int* __restrict__ bc_s, const int* __restrict__ cbase_s,
                         const int* __restrict__ bc_d, const int* __restrict__ cbase_d,
                         int* __restrict__ recs_s, int2* __restrict__ recs_d, int E) {
  __shared__ int cs[NB], cd[NB];
  for (int i = threadIdx.x; i < NB; i += 256) {
    cs[i] = cbase_s[i] + bc_s[blockIdx.x * NB + i];
    cd[i] = cbase_d[i] + bc_d[blockIdx.x * NB + i];
  }
  __syncthreads();
  int e0 = blockIdx.x * EBLK, e1 = min(e0 + EBLK, E);
  for (int i = e0 + threadIdx.x; i < e1; i += 256) {
    int s = src[i], d = dst[i];
    int ps = atomicAdd(&cs[s >> BSH], 1);
    recs_s[ps] = s;
    int pd = atomicAdd(&cd[d >> BSH], 1);
    recs_d[pd] = int2{s | ((d & 127) << 17), __builtin_bit_cast(int, ew[i])};
  }
}

// ---------------- merged fine pass: dst CSR (offs, nd, esw) + src hist (ns) ----------------
__global__ void k_finecomb(const int2* __restrict__ recs_d, const int* __restrict__ cbase_d,
                           const int* __restrict__ recs_s, const int* __restrict__ cbase_s,
                           int2* __restrict__ esw, int* __restrict__ offs,
                           float* __restrict__ nd, float* __restrict__ ns, int N) {
  __shared__ int h[128], cur[128];
  __shared__ int w0tot;
  int bin = blockIdx.x;
  int r0 = cbase_d[bin], r1 = cbase_d[bin + 1];
  int t = threadIdx.x;
  if (t < 128) h[t] = 0;
  __syncthreads();
  for (int i = r0 + t; i < r1; i += 256) atomicAdd(&h[recs_d[i].x >> 17], 1);
  __syncthreads();
  int v = 0, x = 0;
  if (t < 128) {
    v = h[t];
    x = v;
#pragma unroll
    for (int d = 1; d < 64; d <<= 1) { int tt = __shfl_up(x, d); if ((t & 63) >= d) x += tt; }
    if (t == 63) w0tot = x;
  }
  __syncthreads();
  if (t < 128) {
    int excl = x - v + (t >= 64 ? w0tot : 0);
    int node = bin * 128 + t;
    if (node < N) {
      offs[node] = r0 + excl;
      int d = v < 1 ? 1 : v;
      nd[node] = (float)(1.0 / sqrt((double)d));
    }
    cur[t] = r0 + excl;
  }
  __syncthreads();
  for (int i = r0 + t; i < r1; i += 256) {
    int2 rc = recs_d[i];
    int p = atomicAdd(&cur[rc.x >> 17], 1);
    esw[p] = int2{rc.x & 0x1ffff, rc.y};
  }
  // ---- src side: out-degree histogram -> ns ----
  __syncthreads();
  if (t < 128) h[t] = 0;
  __syncthreads();
  int s0 = cbase_s[bin], s1 = cbase_s[bin + 1];
  for (int i = s0 + t; i < s1; i += 256) atomicAdd(&h[recs_s[i] & 127], 1);
  __syncthreads();
  if (t < 128) {
    int node = bin * 128 + t;
    if (node < N) {
      int d = h[t] < 1 ? 1 : h[t];
      ns[node] = (float)(1.0 / sqrt((double)d));
    }
  }
}

// ---------------- merged W split: W1 and W2 -> transposed bf16 hi/lo planes ----------------
__global__ void k_wsplit2(const float* __restrict__ W1, short* __restrict__ w1h,
                          short* __restrict__ w1l, const float* __restrict__ W2,
                          short* __restrict__ w2h, short* __restrict__ w2l) {
  int t = blockIdx.x * blockDim.x + threadIdx.x;
  if (t < D0 * D1) {
    int k = t / D1, n = t % D1;
    float f = W1[t];
    unsigned short h = f2bf(f);
    w1h[(size_t)n * D0 + k] = (short)h;
    w1l[(size_t)n * D0 + k] = (short)f2bf(f - bf2f(h));
  } else if (t < D0 * D1 + D1 * D2) {
    int i = t - D0 * D1;
    int k = i / D2, n = i % D2;
    float f = W2[i];
    unsigned short h = f2bf(f);
    w2h[(size_t)n * D1 + k] = (short)h;
    w2l[(size_t)n * D1 + k] = (short)f2bf(f - bf2f(h));
  }
}

// ---------------- MFMA GEMM (layer 1): C[M,N] = (A * ns[:,None]) @ W ----------------
template <int K, int N, int WR, int WC>
__launch_bounds__(256, 2)
__global__ void k_gemm_mfma(const float* __restrict__ A, const float* __restrict__ ns,
                            const short* __restrict__ Wth, const short* __restrict__ Wtl,
                            float* __restrict__ C, int M) {
  constexpr int MR = 128 / WR / 16;
  constexpr int NC = N / WC / 16;
  __shared__ short8 Ah[4 * 128], Al[4 * 128];
  __shared__ short8 Bh[4 * N], Bl[4 * N];
  const int t = threadIdx.x;
  const int block_row = blockIdx.x * 128;
  const int lane = t & 63, wid = t >> 6;
  const int wr = wid / WC, wc = wid % WC;
  const int rowbase = wr * (128 / WR), colbase = wc * (N / WC);
  const int c = lane >> 4, lr = lane & 15;
  f32x4 acc[MR][NC] = {};
  const int r = t & 127;
  const int grow = block_row + r;
  float nsv = 0.f;
  if (t < 128 && grow < M) nsv = ns[grow];

  for (int k0 = 0; k0 < K; k0 += 32) {
    if (t < 128) {
      f32x4 v[8];
      if (grow < M) {
        const f32x4* ap = (const f32x4*)(A + (size_t)grow * K + k0);
#pragma unroll
        for (int i = 0; i < 8; ++i) v[i] = ap[i] * nsv;
      } else {
#pragma unroll
        for (int i = 0; i < 8; ++i) v[i] = f32x4{0.f, 0.f, 0.f, 0.f};
      }
#pragma unroll
      for (int cc = 0; cc < 4; ++cc) {
        short8 hi, lo;
#pragma unroll
        for (int i = 0; i < 8; ++i) {
          float f = v[cc * 2 + (i >> 2)][i & 3];
          unsigned short h = f2bf(f);
          hi[i] = (short)h;
          lo[i] = (short)f2bf(f - bf2f(h));
        }
        Ah[cc * 128 + r] = hi;
        Al[cc * 128 + r] = lo;
      }
    } else {
      const int tt = t - 128;
#pragma unroll
      for (int id = tt; id < N * 4; id += 128) {
        int col = id & (N - 1);
        int cb = id / N;
        Bh[cb * N + col] = *(const short8*)(Wth + (size_t)col * K + k0 + cb * 8);
        Bl[cb * N + col] = *(const short8*)(Wtl + (size_t)col * K + k0 + cb * 8);
      }
    }
    __syncthreads();
    short8 ah[MR], al[MR], bh[NC], bl[NC];
#pragma unroll
    for (int m = 0; m < MR; ++m) {
      int row = rowbase + m * 16 + lr;
      ah[m] = Ah[c * 128 + row];
      al[m] = Al[c * 128 + row];
    }
#pragma unroll
    for (int n = 0; n < NC; ++n) {
      int col = colbase + n * 16 + lr;
      bh[n] = Bh[c * N + col];
      bl[n] = Bl[c * N + col];
    }
#pragma unroll
    for (int m = 0; m < MR; ++m)
#pragma unroll
      for (int n = 0; n < NC; ++n) {
        acc[m][n] = __builtin_amdgcn_mfma_f32_16x16x32_bf16(ah[m], bh[n], acc[m][n], 0, 0, 0);
        acc[m][n] = __builtin_amdgcn_mfma_f32_16x16x32_bf16(ah[m], bl[n], acc[m][n], 0, 0, 0);
        acc[m][n] = __builtin_amdgcn_mfma_f32_16x16x32_bf16(al[m], bh[n], acc[m][n], 0, 0, 0);
      }
    __syncthreads();
  }
#pragma unroll
  for (int m = 0; m < MR; ++m) {
#pragma unroll
    for (int j = 0; j < 4; ++j) {
      int row = block_row + rowbase + m * 16 + (lane >> 4) * 4 + j;
      if (row < M) {
#pragma unroll
        for (int n = 0; n < NC; ++n)
          C[(size_t)row * N + colbase + n * 16 + lr] = acc[m][n][j];
      }
    }
  }
}

// ---------------- FUSED agg128 + GEMM2: dwordx4 gather, 2 edges per wave-load ----------------
// Half-wave per edge: lane = (hi, p), p=lane&31 covers features 4p..4p+3 (f32x4).
// Halves combined via shfl_xor(32). LDS word mapping unchanged (word w = feats 2w,2w+1).
__launch_bounds__(256, 4)
__global__ void k_agg128f(const float* __restrict__ h, const int* __restrict__ offs,
                          const int2* __restrict__ esw, const float* __restrict__ nd,
                          const float* __restrict__ b1v, const float* __restrict__ ns,
                          const short* __restrict__ w2h, const short* __restrict__ w2l,
                          float* __restrict__ h2, int M) {
  __shared__ unsigned Ah32[16 * 64], Al32[16 * 64];
  const int t = threadIdx.x, lane = t & 63, wid = t >> 6;
  const int base = blockIdx.x * 16;
  const int nb0 = base + wid * 4;
  const f32x4* hp4 = (const f32x4*)h;
  const int p = lane & 31;
  const int hi = lane >> 5;
  f32x4 bv = ((const f32x4*)b1v)[p];
  int ov = offs[min(nb0 + min(lane, 5), M)];
  int S0[4], S1[4];
#pragma unroll
  for (int q = 0; q < 4; ++q) { S0[q] = rdlane_i(ov, q); S1[q] = rdlane_i(ov, q + 1); }
  int2 ecur{0, 0};
  { int kk = S0[0] + lane; if (kk < S1[0]) ecur = esw[kk]; }
#pragma unroll
  for (int q = 0; q < 4; ++q) {
    const int row = wid * 4 + q;
    const int node = nb0 + q;
    int2 enxt{0, 0};
    if (q < 3) { int kk = S0[q + 1] + lane; if (kk < S1[q + 1]) enxt = esw[kk]; }
    unsigned hw0 = 0, hw1 = 0, lw0 = 0, lw1 = 0;
    if (node < M) {
      const int s0 = S0[q], s1 = S1[q];
      f32x4 acc = {};
      int2 e = ecur;
      for (int bb = s0; bb < s1; bb += 64) {
        if (bb != s0) { int kk = bb + lane; e = (kk < s1) ? esw[kk] : int2{0, 0}; }
        int sidx = e.x;
        float wt = __builtin_bit_cast(float, e.y);
        int cnt = min(64, s1 - bb);
        for (int jj = 0; jj < cnt; jj += 16) {
          f32x4 v[8];
#pragma unroll
          for (int u = 0; u < 8; ++u) {
            int r0 = rdlane_i(sidx, jj + 2 * u);
            int r1 = rdlane_i(sidx, jj + 2 * u + 1);
            int s = hi ? r1 : r0;
            v[u] = hp4[(size_t)(unsigned)s * 32 + p];
          }
          __builtin_amdgcn_sched_barrier(0);  // keep all 8 x 1KB gathers in flight
#pragma unroll
          for (int u = 0; u < 8; ++u) {
            float w0 = rdlane_f(wt, jj + 2 * u);
            float w1 = rdlane_f(wt, jj + 2 * u + 1);
            float wu = hi ? w1 : w0;
            acc[0] += v[u][0] * wu;
            acc[1] += v[u][1] * wu;
            acc[2] += v[u][2] * wu;
            acc[3] += v[u][3] * wu;
          }
        }
      }
      f32x4 o;
#pragma unroll
      for (int i = 0; i < 4; ++i) o[i] = acc[i] + __shfl_xor(acc[i], 32);
      float ndv = nd[node], nsv = ns[node];
      float z[4];
#pragma unroll
      for (int i = 0; i < 4; ++i) z[i] = fmaxf(o[i] * ndv + bv[i], 0.f) * nsv;
      unsigned short h0 = f2bf(z[0]), h1b = f2bf(z[1]), h2b = f2bf(z[2]), h3b = f2bf(z[3]);
      hw0 = (unsigned)h0 | ((unsigned)h1b << 16);
      hw1 = (unsigned)h2b | ((unsigned)h3b << 16);
      lw0 = (unsigned)f2bf(z[0] - bf2f(h0)) | ((unsigned)f2bf(z[1] - bf2f(h1b)) << 16);
      lw1 = (unsigned)f2bf(z[2] - bf2f(h2b)) | ((unsigned)f2bf(z[3] - bf2f(h3b)) << 16);
    }
    if (lane < 32) {
      int widx = (2 * p) ^ ((row & 7) << 2);  // XOR swizzle, preserves word pairing
      *(uint2*)&Ah32[row * 64 + widx] = uint2{hw0, hw1};
      *(uint2*)&Al32[row * 64 + widx] = uint2{lw0, lw1};
    }
    ecur = enxt;
  }
  __syncthreads();
  // B-frags for this wave's 16-col tile of W2 ([64][128] bf16 planes)
  const int colB = wid * 16 + (lane & 15);
  const int koff = (lane >> 4) * 8;
  short8 bh[4], bl[4];
#pragma unroll
  for (int ks = 0; ks < 4; ++ks) {
    bh[ks] = *(const short8*)(w2h + (size_t)colB * 128 + ks * 32 + koff);
    bl[ks] = *(const short8*)(w2l + (size_t)colB * 128 + ks * 32 + koff);
  }
  const int arow = lane & 15, ac = lane >> 4;
  f32x4 acc = {};
#pragma unroll
  for (int ks = 0; ks < 4; ++ks) {
    int bidx = arow * 64 + ((ks * 16 + ac * 4) ^ ((arow & 7) << 2));
    short8 ah = *(const short8*)(Ah32 + bidx);
    short8 al = *(const short8*)(Al32 + bidx);
    acc = __builtin_amdgcn_mfma_f32_16x16x32_bf16(ah, bh[ks], acc, 0, 0, 0);
    acc = __builtin_amdgcn_mfma_f32_16x16x32_bf16(ah, bl[ks], acc, 0, 0, 0);
    acc = __builtin_amdgcn_mfma_f32_16x16x32_bf16(al, bh[ks], acc, 0, 0, 0);
  }
  const int crow = (lane >> 4) * 4;
  const int col = wid * 16 + (lane & 15);
#pragma unroll
  for (int j = 0; j < 4; ++j) {
    int node = base + crow + j;
    if (node < M) h2[(size_t)node * 64 + col] = acc[j];
  }
}

// ---------------- agg64+matvec: dwordx4 gather, 4 edges per wave-load ----------------
// Quarter-wave per edge: p=lane&15 covers features 4p..4p+3; quarters combined
// via shfl_xor(16,32); W3 dot reduced over 16 lanes.
__global__ void k_agg64mv(const float* __restrict__ h, const int* __restrict__ offs,
                          const int2* __restrict__ esw, const float* __restrict__ nd,
                          const float* __restrict__ b2, const float* __restrict__ W3,
                          const float* __restrict__ ns, float* __restrict__ h3, int M) {
  const int lane = threadIdx.x & 63;
  const int wave = blockIdx.x * (blockDim.x >> 6) + (threadIdx.x >> 6);
  const int nb0 = wave * 4;
  if (nb0 >= M) return;
  const f32x4* hp4 = (const f32x4*)h;
  const int p = lane & 15;
  const int q4 = lane >> 4;
  const bool qb0 = q4 & 1, qb1 = q4 & 2;
  f32x4 bv = ((const f32x4*)b2)[p];
  f32x4 w3v = ((const f32x4*)W3)[p];
  int ov = offs[min(nb0 + min(lane, 5), M)];
  int S0[4], S1[4];
#pragma unroll
  for (int q = 0; q < 4; ++q) { S0[q] = rdlane_i(ov, q); S1[q] = rdlane_i(ov, q + 1); }
  int2 ecur{0, 0};
  { int kk = S0[0] + lane; if (kk < S1[0]) ecur = esw[kk]; }
#pragma unroll
  for (int q = 0; q < 4; ++q) {
    const int node = nb0 + q;
    int2 enxt{0, 0};
    if (q < 3) { int kk = S0[q + 1] + lane; if (kk < S1[q + 1]) enxt = esw[kk]; }
    if (node < M) {
      const int s0 = S0[q], s1 = S1[q];
      f32x4 acc = {};
      int2 e = ecur;
      for (int bb = s0; bb < s1; bb += 64) {
        if (bb != s0) { int kk = bb + lane; e = (kk < s1) ? esw[kk] : int2{0, 0}; }
        int sidx = e.x;
        float wt = __builtin_bit_cast(float, e.y);
        int cnt = min(64, s1 - bb);
        for (int jj = 0; jj < cnt; jj += 32) {
          f32x4 v[8];
#pragma unroll
          for (int u = 0; u < 8; ++u) {
            int ei = jj + 4 * u;
            int r0 = rdlane_i(sidx, ei), r1 = rdlane_i(sidx, ei + 1);
            int r2 = rdlane_i(sidx, ei + 2), r3 = rdlane_i(sidx, ei + 3);
            int c01 = qb0 ? r1 : r0;
            int c23 = qb0 ? r3 : r2;
            int s = qb1 ? c23 : c01;
            v[u] = hp4[(size_t)(unsigned)s * 16 + p];
          }
          __builtin_amdgcn_sched_barrier(0);  // keep all 8 x 1KB gathers in flight
#pragma unroll
          for (int u = 0; u < 8; ++u) {
            int ei = jj + 4 * u;
            float w0 = rdlane_f(wt, ei), w1 = rdlane_f(wt, ei + 1);
            float w2 = rdlane_f(wt, ei + 2), w3s = rdlane_f(wt, ei + 3);
            float c01 = qb0 ? w1 : w0;
            float c23 = qb0 ? w3s : w2;
            float wu = qb1 ? c23 : c01;
            acc[0] += v[u][0] * wu;
            acc[1] += v[u][1] * wu;
            acc[2] += v[u][2] * wu;
            acc[3] += v[u][3] * wu;
          }
        }
      }
#pragma unroll
      for (int i = 0; i < 4; ++i) {
        acc[i] += __shfl_xor(acc[i], 16);
        acc[i] += __shfl_xor(acc[i], 32);
      }
      float ndv = nd[node];
      float dp = 0.f;
#pragma unroll
      for (int i = 0; i < 4; ++i) dp += fmaxf(acc[i] * ndv + bv[i], 0.f) * w3v[i];
#pragma unroll
      for (int d = 8; d; d >>= 1) dp += __shfl_xor(dp, d);
      if (lane == 0) h3[node] = dp * ns[node];
    }
    ecur = enxt;
  }
}

// ---------------- final scalar aggregation ----------------
__global__ void k_aggfin(const float* __restrict__ h3, const int* __restrict__ offs,
                         const int2* __restrict__ esw, const float* __restrict__ nd,
                         const float* __restrict__ b3, float* __restrict__ out, int M) {
  int i = blockIdx.x * blockDim.x + threadIdx.x;
  if (i >= M) return;
  int s0 = offs[i], s1 = offs[i + 1];
  float acc = 0.f;
  int k = s0;
  for (; k + 4 <= s1; k += 4) {
    int2 e0 = esw[k], e1 = esw[k + 1], e2 = esw[k + 2], e3 = esw[k + 3];
    acc += h3[e0.x] * __builtin_bit_cast(float, e0.y)
         + h3[e1.x] * __builtin_bit_cast(float, e1.y)
         + h3[e2.x] * __builtin_bit_cast(float, e2.y)
         + h3[e3.x] * __builtin_bit_cast(float, e3.y);
  }
  for (; k < s1; ++k) {
    int2 e = esw[k];
    acc += h3[e.x] * __builtin_bit_cast(float, e.y);
  }
  out[i] = acc * nd[i] + b3[0];
}

extern "C" void kernel_launch(void* const* d_in, const int* in_sizes, int n_in,
                              void* d_out, int out_size, void* d_ws, size_t ws_size,
                              hipStream_t stream) {
  const float* b_z = (const float*)d_in[0];
  const int*   src = (const int*)d_in[1];
  const int*   dst = (const int*)d_in[2];
  const float* ew  = (const float*)d_in[3];
  const float* W1  = (const float*)d_in[5];
  const float* b1  = (const float*)d_in[6];
  const float* W2  = (const float*)d_in[7];
  const float* b2  = (const float*)d_in[8];
  const float* W3  = (const float*)d_in[9];
  const float* b3  = (const float*)d_in[10];
  const int N = in_sizes[0] / D0;
  const int E = in_sizes[1];
  float* out = (float*)d_out;

  char* ws = (char*)d_ws;
  size_t off_b = 0;
  auto alloc = [&](size_t bytes) -> void* {
    void* p = ws + off_b;
    off_b += (bytes + 255) & ~(size_t)255;
    return p;
  };
  const int nbk = (E + EBLK - 1) / EBLK;
  int*   bc_s    = (int*)alloc((size_t)nbk * NB * 4);
  int*   bc_d    = (int*)alloc((size_t)nbk * NB * 4);
  int*   bt_s    = (int*)alloc((size_t)NB * 4);
  int*   bt_d    = (int*)alloc((size_t)NB * 4);
  int*   cbase_s = (int*)alloc((size_t)(NB + 1) * 4);
  int*   cbase_d = (int*)alloc((size_t)(NB + 1) * 4);
  int*   offs    = (int*)alloc((size_t)(N + 1) * 4);
  int2*  esw     = (int2*)alloc((size_t)E * 8);
  float* nsrc    = (float*)alloc((size_t)N * 4);
  float* ndst    = (float*)alloc((size_t)N * 4);
  float* h1      = (float*)alloc((size_t)N * D1 * 4);  // 51.2 MB
  float* h2      = (float*)alloc((size_t)N * D2 * 4);  // 25.6 MB
  float* h3      = (float*)alloc((size_t)N * 4);
  short* wt1h    = (short*)alloc((size_t)D0 * D1 * 2);
  short* wt1l    = (short*)alloc((size_t)D0 * D1 * 2);
  short* wt2h    = (short*)alloc((size_t)D1 * D2 * 2);
  short* wt2l    = (short*)alloc((size_t)D1 * D2 * 2);
  // partition records alias h1 (both dead before GEMM1 writes h1)
  int2*  recs_d = (int2*)h1;                              // E*8 = 12.8 MB
  int*   recs_s = (int*)((char*)h1 + ((size_t)16 << 20)); // E*4 = 6.4 MB @ +16MB

  // --- CSR build (atomic-free, fully parallel) ---
  k_chist2<<<nbk, 256, 0, stream>>>(src, dst, bc_s, bc_d, E);
  k_binscan<<<dim3(NB / 16, 2), 256, 0, stream>>>(bc_s, bt_s, bc_d, bt_d, nbk);
  k_btscan<<<2, 1024, 0, stream>>>(bt_s, cbase_s, bt_d, cbase_d, &offs[N], E);
  k_cpart2<<<nbk, 256, 0, stream>>>(src, dst, ew, bc_s, cbase_s, bc_d, cbase_d,
                                    recs_s, recs_d, E);
  k_finecomb<<<NB, 256, 0, stream>>>(recs_d, cbase_d, recs_s, cbase_s, esw, offs,
                                     ndst, nsrc, N);
  k_wsplit2<<<(D0 * D1 + D1 * D2 + 255) / 256, 256, 0, stream>>>(W1, wt1h, wt1l,
                                                                 W2, wt2h, wt2l);

  // layer 1: 256 -> 128 (MFMA)
  k_gemm_mfma<D0, D1, 2, 2><<<(N + 127) / 128, 256, 0, stream>>>(b_z, nsrc, wt1h, wt1l, h1, N);
  // layer-1 agg + layer-2 projection fused (writes h2 directly, no z1)
  k_agg128f<<<(N + 15) / 16, 256, 0, stream>>>(h1, offs, esw, ndst, b1, nsrc,
                                               wt2h, wt2l, h2, N);
  // layer-2 agg fused with layer-3 projection (64->1 matvec)
  k_agg64mv<<<(N + 15) / 16, 256, 0, stream>>>(h2, offs, esw, ndst, b2, W3, nsrc, h3, N);
  // final scalar aggregation
  k_aggfin<<<(N + 255) / 256, 256, 0, stream>>>(h3, offs, esw, ndst, b3, out, N);
}